// Round 17
// baseline (647.973 us; speedup 1.0000x reference)
//
#include <hip/hip_runtime.h>
#include <float.h>

#define B_ 16
#define N_ 2048
#define KNN 20
#define WBAR() __builtin_amdgcn_wave_barrier()

typedef unsigned short u16;
typedef __attribute__((ext_vector_type(8))) short bf16x8;
typedef __attribute__((ext_vector_type(4))) float f32x4;

typedef const __attribute__((address_space(1))) unsigned gas_t;
typedef __attribute__((address_space(3))) unsigned las_t;

__device__ inline u16 bfhi(float v) {
    union { float f; unsigned u; } x; x.f = v;
    unsigned r = x.u + 0x7FFFu + ((x.u >> 16) & 1u);
    return (u16)(r >> 16);
}
__device__ inline u16 bflo(float v, u16 h) {
    union { unsigned u; float f; } y; y.u = ((unsigned)h) << 16;
    return bfhi(v - y.f);
}
__device__ inline unsigned fkey(float v) {
    union { float f; unsigned u; } x;
    x.f = fmaxf(v, 0.f);
    return x.u & 0x7FFFFFFFu;
}
__device__ inline u16 fkey16(float v) { return (u16)(fkey(v) >> 15); }
__device__ inline unsigned umin_(unsigned a, unsigned b) { return a < b ? a : b; }

// payload (element index) encoding per keys-per-lane layout
template <int MODE>
__device__ inline unsigned payof(int i, int lane) {
    if (MODE == 0) return ((unsigned)(i >> 2) << 8) + (unsigned)lane * 4u + (unsigned)(i & 3);
    else           return ((unsigned)(i >> 3) << 9) + (unsigned)lane * 8u + (unsigned)(i & 7);
}

// ---------------- bitonic sort across 64 lanes (ascending by key) ----------------
template <bool P>
__device__ inline void bitonic64(unsigned& key, unsigned& pay, int lane) {
#pragma unroll
    for (int k = 2; k <= 64; k <<= 1) {
#pragma unroll
        for (int j = k >> 1; j > 0; j >>= 1) {
            unsigned ok = __shfl_xor(key, j);
            unsigned op = P ? __shfl_xor(pay, j) : 0u;
            bool up = ((lane & k) == 0);
            bool lower = ((lane & j) == 0);
            bool takeOther = (up == lower) ? (ok < key) : (ok > key);
            if (takeOther) { key = ok; if (P) pay = op; }
        }
    }
}

// finish one query from its survivor lists (sorted path or exact fallback)
template <int MODE>
__device__ inline void finish_one(const unsigned* kr, unsigned stot,
                                  unsigned* klist, unsigned* ilist, int lane,
                                  int* __restrict__ outIdx) {
    if (stot <= 64u) {
        unsigned key = klist[lane], pay = ilist[lane];
        bitonic64<true>(key, pay, lane);
        if (lane < KNN) outIdx[lane] = (int)pay;
    } else {
        unsigned taken = 0;
        for (int it = 0; it < KNN; ++it) {
            unsigned bk = 0xFFFFFFFFu; int bi = 0;
#pragma unroll
            for (int i = 0; i < 32; ++i) {
                bool better = (((taken >> i) & 1u) == 0u) && (kr[i] < bk);
                if (better) { bk = kr[i]; bi = i; }
            }
            unsigned bl = (unsigned)lane;
#pragma unroll
            for (int off = 32; off > 0; off >>= 1) {
                unsigned ok = __shfl_down(bk, off);
                unsigned ol = __shfl_down(bl, off);
                int oi = __shfl_down(bi, off);
                if (ok < bk) { bk = ok; bl = ol; bi = oi; }
            }
            bl = __shfl(bl, 0); bi = __shfl(bi, 0);
            if (lane == (int)bl) taken |= (1u << bi);
            if (lane == 0) outIdx[it] = (int)payof<MODE>(bi, (int)bl);
        }
    }
}

// ---------------- DUAL top-20: two queries per wave, interleaved chains ----------------
template <int MODE>
__device__ inline void select20_pair(const unsigned kr[2][32], int lane,
                                     unsigned* kl0, unsigned* il0,
                                     unsigned* kl1, unsigned* il1,
                                     int* __restrict__ o0, int* __restrict__ o1) {
    unsigned lm0 = kr[0][0], lm1 = kr[1][0];
#pragma unroll
    for (int i = 1; i < 32; ++i) { lm0 = umin_(lm0, kr[0][i]); lm1 = umin_(lm1, kr[1][i]); }
    unsigned sk0 = lm0, sk1 = lm1;
#pragma unroll
    for (int k = 2; k <= 64; k <<= 1) {
#pragma unroll
        for (int j = k >> 1; j > 0; j >>= 1) {
            unsigned a0 = __shfl_xor(sk0, j);
            unsigned a1 = __shfl_xor(sk1, j);
            bool up = ((lane & k) == 0), lower = ((lane & j) == 0);
            if ((up == lower) ? (a0 < sk0) : (a0 > sk0)) sk0 = a0;
            if ((up == lower) ? (a1 < sk1) : (a1 > sk1)) sk1 = a1;
        }
    }
    unsigned S0 = __shfl(sk0, 19), S1 = __shfl(sk1, 19);
    unsigned c0 = 0, c1 = 0;
#pragma unroll
    for (int i = 0; i < 32; ++i) {
        c0 += (kr[0][i] <= S0) ? 1u : 0u;
        c1 += (kr[1][i] <= S1) ? 1u : 0u;
    }
    unsigned i0 = c0, i1 = c1;
#pragma unroll
    for (int d = 1; d < 64; d <<= 1) {
        unsigned t0 = __shfl_up(i0, d);
        unsigned t1 = __shfl_up(i1, d);
        if (lane >= d) { i0 += t0; i1 += t1; }
    }
    unsigned st0 = __shfl(i0, 63), st1 = __shfl(i1, 63);
    unsigned p0 = i0 - c0, p1 = i1 - c1;
    kl0[lane] = 0xFFFFFFFFu;
    kl1[lane] = 0xFFFFFFFFu;
    WBAR();
#pragma unroll
    for (int i = 0; i < 32; ++i) {
        if (kr[0][i] <= S0) {
            if (p0 < 64u) { kl0[p0] = kr[0][i]; il0[p0] = payof<MODE>(i, lane); }
            ++p0;
        }
        if (kr[1][i] <= S1) {
            if (p1 < 64u) { kl1[p1] = kr[1][i]; il1[p1] = payof<MODE>(i, lane); }
            ++p1;
        }
    }
    WBAR();
    if (st0 <= 64u && st1 <= 64u) {
        unsigned k0 = kl0[lane], q0 = il0[lane];
        unsigned k1 = kl1[lane], q1 = il1[lane];
#pragma unroll
        for (int k = 2; k <= 64; k <<= 1) {
#pragma unroll
            for (int j = k >> 1; j > 0; j >>= 1) {
                unsigned a0 = __shfl_xor(k0, j), b0 = __shfl_xor(q0, j);
                unsigned a1 = __shfl_xor(k1, j), b1 = __shfl_xor(q1, j);
                bool up = ((lane & k) == 0), lower = ((lane & j) == 0);
                if ((up == lower) ? (a0 < k0) : (a0 > k0)) { k0 = a0; q0 = b0; }
                if ((up == lower) ? (a1 < k1) : (a1 > k1)) { k1 = a1; q1 = b1; }
            }
        }
        if (lane < KNN) { o0[lane] = (int)q0; o1[lane] = (int)q1; }
    } else {
        finish_one<MODE>(kr[0], st0, kl0, il0, lane, o0);
        finish_one<MODE>(kr[1], st1, kl1, il1, lane, o1);
    }
}

// select for convs 2-4: 2 queries per wave, 8 per block
__launch_bounds__(256)
__global__ void select_kernel(const u16* __restrict__ dist, int* __restrict__ idx_out) {
    __shared__ unsigned kl[4][2][64], il[4][2][64];
    int tid = threadIdx.x, w = tid >> 6, lane = tid & 63;
    size_t q0 = (size_t)blockIdx.x * 8 + w * 2;
    const u16* s0 = dist + q0 * N_;
    const u16* s1 = s0 + N_;
    unsigned kr[2][32];
#pragma unroll
    for (int j = 0; j < 4; ++j) {
        uint4 v0 = *(const uint4*)&s0[j * 512 + lane * 8];
        uint4 v1 = *(const uint4*)&s1[j * 512 + lane * 8];
        const unsigned* w0 = (const unsigned*)&v0;
        const unsigned* w1 = (const unsigned*)&v1;
#pragma unroll
        for (int e = 0; e < 4; ++e) {
            kr[0][j * 8 + 2 * e]     = w0[e] & 0xFFFFu;
            kr[0][j * 8 + 2 * e + 1] = w0[e] >> 16;
            kr[1][j * 8 + 2 * e]     = w1[e] & 0xFFFFu;
            kr[1][j * 8 + 2 * e + 1] = w1[e] >> 16;
        }
    }
    select20_pair<1>(kr, lane, kl[w][0], il[w][0], kl[w][1], il[w][1],
                     idx_out + q0 * KNN, idx_out + (q0 + 1) * KNN);
}

// select for conv1: 2 queries per wave, 16 per block (2 rounds)
__launch_bounds__(256)
__global__ void select3_kernel(const float* __restrict__ x, int* __restrict__ idx_out) {
    __shared__ __align__(16) float cx[N_], cy[N_], cz[N_];
    __shared__ unsigned kl[4][2][64], il[4][2][64];
    int tid = threadIdx.x, blk = blockIdx.x;
    int b = blk >> 7, n0 = (blk & 127) * 16;
    for (int i = tid; i < N_; i += 256) {
        const float* p = x + (size_t)(b * N_ + i) * 3;
        cx[i] = p[0]; cy[i] = p[1]; cz[i] = p[2];
    }
    __syncthreads();
    int w = tid >> 6, lane = tid & 63;
    for (int r = 0; r < 2; ++r) {
        int q0 = n0 + r * 8 + w * 2;
        float qx0 = cx[q0], qy0 = cy[q0], qz0 = cz[q0];
        float qx1 = cx[q0 + 1], qy1 = cy[q0 + 1], qz1 = cz[q0 + 1];
        unsigned kr[2][32];
#pragma unroll
        for (int j = 0; j < 8; ++j) {
            float4 vx = *(const float4*)&cx[j * 256 + lane * 4];
            float4 vy = *(const float4*)&cy[j * 256 + lane * 4];
            float4 vz = *(const float4*)&cz[j * 256 + lane * 4];
            const float* px = (const float*)&vx;
            const float* py = (const float*)&vy;
            const float* pz = (const float*)&vz;
#pragma unroll
            for (int e = 0; e < 4; ++e) {
                float X = px[e], Y = py[e], Z = pz[e];
                float dx = qx0 - X, dy = qy0 - Y, dz = qz0 - Z;
                kr[0][j * 4 + e] = fkey(fmaf(dx, dx, fmaf(dy, dy, dz * dz)));
                dx = qx1 - X; dy = qy1 - Y; dz = qz1 - Z;
                kr[1][j * 4 + e] = fkey(fmaf(dx, dx, fmaf(dy, dy, dz * dz)));
            }
        }
        select20_pair<0>(kr, lane, kl[w][0], il[w][0], kl[w][1], il[w][1],
                         idx_out + ((size_t)(b * N_ + q0)) * KNN,
                         idx_out + ((size_t)(b * N_ + q0 + 1)) * KNN);
    }
}

// ---------------- batched weight prep: w5 + 3 edge-Bs + conv1 wt + biases ----------------
__global__ void prep_all_kernel(const float* __restrict__ w1, const float* __restrict__ b1,
                                const float* __restrict__ w2, const float* __restrict__ b2,
                                const float* __restrict__ w3, const float* __restrict__ b3,
                                const float* __restrict__ w4, const float* __restrict__ b4,
                                const float* __restrict__ w5,
                                u16* __restrict__ Bw5h, u16* __restrict__ Bw5l,
                                u16* __restrict__ Be2h, u16* __restrict__ Be2l,
                                u16* __restrict__ Be3h, u16* __restrict__ Be3l,
                                u16* __restrict__ Be4h, u16* __restrict__ Be4l,
                                float* __restrict__ bt2, float* __restrict__ bt3,
                                float* __restrict__ bt4,
                                float* __restrict__ wtf, float* __restrict__ bt1) {
    int t = blockIdx.x * 256 + threadIdx.x;
    if (t < 524288) {
        int n = t / 512, k = t % 512;
        float v = w5[(size_t)k * 1024 + n];
        u16 h = bfhi(v);
        Bw5h[t] = h; Bw5l[t] = bflo(v, h);
    } else if (t < 532480) {
        int e = t - 524288;
        int d = e / 64, c = e % 64;
        float v = (d < 64) ? w2[c * 64 + d] : (w2[(64 + c) * 64 + (d - 64)] - w2[c * 64 + (d - 64)]);
        u16 h = bfhi(v);
        Be2h[e] = h; Be2l[e] = bflo(v, h);
    } else if (t < 548864) {
        int e = t - 532480;
        int d = e / 64, c = e % 64;
        float v = (d < 128) ? w3[c * 128 + d] : (w3[(64 + c) * 128 + (d - 128)] - w3[c * 128 + (d - 128)]);
        u16 h = bfhi(v);
        Be3h[e] = h; Be3l[e] = bflo(v, h);
    } else if (t < 614400) {
        int e = t - 548864;
        int d = e / 128, c = e % 128;
        float v = (d < 256) ? w4[c * 256 + d] : (w4[(128 + c) * 256 + (d - 256)] - w4[c * 256 + (d - 256)]);
        u16 h = bfhi(v);
        Be4h[e] = h; Be4l[e] = bflo(v, h);
    } else if (t < 614528) {
        int e = t - 614400;
        bt2[e] = (e < 64) ? 0.f : b2[e - 64];
    } else if (t < 614784) {
        int e = t - 614528;
        bt3[e] = (e < 128) ? 0.f : b3[e - 128];
    } else if (t < 615296) {
        int e = t - 614784;
        bt4[e] = (e < 256) ? 0.f : b4[e - 256];
    } else if (t < 615680) {
        int e = t - 615296;
        int c = e / 128, d = e % 128;
        float v = (d < 64) ? w1[c * 64 + d] : (w1[(3 + c) * 64 + (d - 64)] - w1[c * 64 + (d - 64)]);
        wtf[e] = v;
    } else if (t < 615808) {
        int e = t - 615680;
        bt1[e] = (e < 64) ? 0.f : b1[e - 64];
    }
}

// ---------------- bf16 MFMA GEMM, 128x128 tile, 4 waves (2x2) ----------------
// EPI 0/1: SPLIT-2 product (aH*bH + aH*bL), XCD-chunked mapping.
// EPI=3: u16 dist keys, HI-ONLY product (1 MFMA), symmetric upper-triangle grid.
template <int EPI>
__launch_bounds__(256, 2)
__global__ void mfma_gemm(const u16* __restrict__ Ah,
                          long long aZ, int lda,
                          const u16* __restrict__ Bh, const u16* __restrict__ Bl,
                          long long bZ, int ldb,
                          const float* __restrict__ ep, long long epZ,
                          float* __restrict__ out, long long outZ, int ldo,
                          int K) {
    __shared__ __align__(16) char smem[73728];
    u16* AsH = (u16*)(smem);
    u16* BsH = (u16*)(smem + 16384);
    u16* BsL = (u16*)(smem + 32768);
    u16 (*LTs)[136] = (u16(*)[136])(smem);
    __shared__ float red[2][128];
    int tid = threadIdx.x;
    int m0, n0, mt = 0;
    if (EPI == 3) {
        int t = blockIdx.x, rem = 16, bi = 0;
        while (t >= rem) { t -= rem; ++bi; --rem; }
        m0 = bi * 128; n0 = (bi + t) * 128;
    } else {
        int MT = gridDim.x, NT = gridDim.y;
        int f = blockIdx.x + blockIdx.y * MT;
        int xcd = f & 7, s = f >> 3;
        int sm = s / NT;
        int nt = s - sm * NT;
        mt = xcd * (MT >> 3) + sm;
        m0 = mt * 128; n0 = nt * 128;
    }
    int z = blockIdx.z;
    const u16* ah = Ah + (size_t)z * aZ;
    const u16* bh = Bh + (size_t)z * bZ;
    const u16* bl = Bl + (size_t)z * bZ;
    const float* epz = ep + (size_t)z * epZ;
    float* op = out + (size_t)z * outZ;

    int wid = tid >> 6, lane = tid & 63;
    int wm = wid >> 1, wn = wid & 1;
    int l15 = lane & 15, l4 = lane >> 4;
    int lrow8 = lane >> 3;
    int lg = lane & 7;

    f32x4 acc[4][4];
#pragma unroll
    for (int i = 0; i < 4; ++i)
#pragma unroll
        for (int j = 0; j < 4; ++j) acc[i][j] = (f32x4){0.f, 0.f, 0.f, 0.f};

    for (int k0 = 0; k0 < K; k0 += 64) {
        if (k0) __syncthreads();
#pragma unroll
        for (int ch = 0; ch < 4; ++ch) {
            int row = wid * 32 + ch * 8 + lrow8;
            int gsrc = lg ^ (row & 7);
            unsigned ldsoff = (unsigned)(wid * 32 + ch * 8) * 64;
            size_t ga = (size_t)(m0 + row) * lda + k0 + gsrc * 8;
            size_t gb = (size_t)(n0 + row) * ldb + k0 + gsrc * 8;
            __builtin_amdgcn_global_load_lds((gas_t*)(ah + ga), (las_t*)(AsH + ldsoff), 16, 0, 0);
            __builtin_amdgcn_global_load_lds((gas_t*)(bh + gb), (las_t*)(BsH + ldsoff), 16, 0, 0);
            if (EPI != 3)
                __builtin_amdgcn_global_load_lds((gas_t*)(bl + gb), (las_t*)(BsL + ldsoff), 16, 0, 0);
        }
        __syncthreads();
#pragma unroll
        for (int kk = 0; kk < 2; ++kk) {
            int ko_g = kk * 4 + l4;
            bf16x8 aH[4], bH[4], bL[4];
#pragma unroll
            for (int i = 0; i < 4; ++i) {
                int ra = wm * 64 + i * 16 + l15;
                int oa = ra * 64 + ((ko_g ^ (ra & 7)) << 3);
                aH[i] = *(const bf16x8*)&AsH[oa];
                int rb = wn * 64 + i * 16 + l15;
                int ob = rb * 64 + ((ko_g ^ (rb & 7)) << 3);
                bH[i] = *(const bf16x8*)&BsH[ob];
                if (EPI != 3) bL[i] = *(const bf16x8*)&BsL[ob];
            }
#pragma unroll
            for (int i = 0; i < 4; ++i)
#pragma unroll
                for (int j = 0; j < 4; ++j) {
                    acc[i][j] = __builtin_amdgcn_mfma_f32_16x16x32_bf16(aH[i], bH[j], acc[i][j], 0, 0, 0);
                    if (EPI != 3)
                        acc[i][j] = __builtin_amdgcn_mfma_f32_16x16x32_bf16(aH[i], bL[j], acc[i][j], 0, 0, 0);
                }
        }
    }

    if (EPI == 0) {
#pragma unroll
        for (int i = 0; i < 4; ++i)
#pragma unroll
            for (int r = 0; r < 4; ++r) {
                int grow = m0 + wm * 64 + i * 16 + l4 * 4 + r;
#pragma unroll
                for (int j = 0; j < 4; ++j) {
                    int col = n0 + wn * 64 + j * 16 + l15;
                    op[(size_t)grow * ldo + col] = acc[i][j][r] + epz[col];
                }
            }
    } else if (EPI == 1) {
        float pm[4];
#pragma unroll
        for (int j = 0; j < 4; ++j) {
            float v = -FLT_MAX;
#pragma unroll
            for (int i = 0; i < 4; ++i)
#pragma unroll
                for (int r = 0; r < 4; ++r) v = fmaxf(v, acc[i][j][r]);
            v = fmaxf(v, __shfl_xor(v, 16));
            v = fmaxf(v, __shfl_xor(v, 32));
            pm[j] = v;
        }
        if (l4 == 0) {
#pragma unroll
            for (int j = 0; j < 4; ++j) red[wm][wn * 64 + j * 16 + l15] = pm[j];
        }
        __syncthreads();
        if (tid < 128) {
            float v = fmaxf(red[0][tid], red[1][tid]) + epz[n0 + tid];
            v = (v > 0.f) ? v : 0.2f * v;
            op[(size_t)mt * ldo + n0 + tid] = v;
        }
    } else {
        u16* opu = (u16*)op;
#pragma unroll
        for (int i = 0; i < 4; ++i)
#pragma unroll
            for (int r = 0; r < 4; ++r) {
                int grow = m0 + wm * 64 + i * 16 + l4 * 4 + r;
                float sm = epz[grow];
#pragma unroll
                for (int j = 0; j < 4; ++j) {
                    int col = n0 + wn * 64 + j * 16 + l15;
                    opu[(size_t)grow * ldo + col] = fkey16(sm + epz[col] - 2.f * acc[i][j][r]);
                }
            }
        if (m0 != n0) {
            __syncthreads();
#pragma unroll
            for (int i = 0; i < 4; ++i)
#pragma unroll
                for (int j = 0; j < 4; ++j) {
                    int colL  = wn * 64 + j * 16 + l15;
                    int growL = wm * 64 + i * 16 + l4 * 4;
                    unsigned k0v = fkey16(epz[m0 + growL + 0] + epz[n0 + colL] - 2.f * acc[i][j][0]);
                    unsigned k1v = fkey16(epz[m0 + growL + 1] + epz[n0 + colL] - 2.f * acc[i][j][1]);
                    unsigned k2v = fkey16(epz[m0 + growL + 2] + epz[n0 + colL] - 2.f * acc[i][j][2]);
                    unsigned k3v = fkey16(epz[m0 + growL + 3] + epz[n0 + colL] - 2.f * acc[i][j][3]);
                    uint2 pk;
                    pk.x = k0v | (k1v << 16);
                    pk.y = k2v | (k3v << 16);
                    *(uint2*)&LTs[colL][growL] = pk;
                }
            __syncthreads();
            for (int rr0 = 0; rr0 < 128; rr0 += 8) {
                int rr = rr0 + (tid >> 5), cc = (tid & 31) * 4;
                uint2 v = *(const uint2*)&LTs[rr][cc];
                *(uint2*)&opu[(size_t)(n0 + rr) * ldo + m0 + cc] = v;
            }
        }
    }
}

// ---------------- conv1 direct GEMM (K=3) ----------------
__global__ void conv1_kernel(const float* __restrict__ x, const float* __restrict__ wt,
                             const float* __restrict__ bt, float* __restrict__ ut) {
    __shared__ float sw[3][128], sb[128];
    int tid = threadIdx.x;
    if (tid < 128) { sw[0][tid] = wt[tid]; sw[1][tid] = wt[128 + tid]; }
    else { int d = tid - 128; sw[2][d] = wt[256 + d]; sb[d] = bt[d]; }
    __syncthreads();
    int t = blockIdx.x * 256 + tid;
    int m = t >> 7, d = t & 127;
    const float* xm = x + (size_t)m * 3;
    float v = sb[d];
    v = fmaf(xm[0], sw[0][d], v);
    v = fmaf(xm[1], sw[1][d], v);
    v = fmaf(xm[2], sw[2][d], v);
    ut[(size_t)m * 128 + d] = v;
}

// ---------------- gather + leaky + max over k + fused next-conv sqnorm ----------------
template <int COUT>
__global__ void gather_max_kernel(const float* __restrict__ ut,
                                  const int* __restrict__ idx,
                                  u16* __restrict__ cathi, u16* __restrict__ catlo,
                                  int coloff, float* __restrict__ sqn_out) {
    const int P = 256 / COUT;
    int tid = threadIdx.x;
    int p = tid / COUT, d = tid % COUT;
    int nb = gridDim.x;
    int i = blockIdx.x;
    int half = (i >= (nb >> 1)) ? 1 : 0;
    int ii = i - half * (nb >> 1);
    int b = half * 8 + (ii & 7);
    int within = ii >> 3;
    int pt_base = b * 2048 + within * P;
    int pt = pt_base + p;
    int n = pt & 2047;
    __shared__ int sidx[P][KNN];
    __shared__ float wpart[4];
    for (int q = tid; q < P * KNN; q += 256) {
        int pp = q / KNN, kk = q % KNN;
        sidx[pp][kk] = idx[(size_t)(pt_base + pp) * KNN + kk];
    }
    __syncthreads();
    const int N2 = 2 * COUT;
    const float* utb = ut + (size_t)b * N_ * N2;
    float tval = utb[(size_t)n * N2 + COUT + d];
    float acc = -FLT_MAX;
#pragma unroll
    for (int k = 0; k < KNN; k++) {
        int j = __builtin_amdgcn_readfirstlane(sidx[p][k]);
        const float* rp = utb + (size_t)j * N2;
        float s = rp[d] + tval;
        s = (s > 0.f) ? s : 0.2f * s;
        acc = fmaxf(acc, s);
    }
    u16 h = bfhi(acc);
    u16 l = bflo(acc, h);
    cathi[(size_t)pt * 512 + coloff + d] = h;
    catlo[(size_t)pt * 512 + coloff + d] = l;
    if (sqn_out) {
        union { unsigned u; float f; } va, vb;
        va.u = ((unsigned)h) << 16; vb.u = ((unsigned)l) << 16;
        float v = va.f + vb.f;
        float sq = v * v;
#pragma unroll
        for (int off = 1; off < 64; off <<= 1) sq += __shfl_xor(sq, off);
        int wid = tid >> 6, lane = tid & 63;
        if (lane == 0) wpart[wid] = sq;
        __syncthreads();
        const int WPP = COUT / 64;
        if (tid < P) {
            float s2 = 0.f;
#pragma unroll
            for (int ww = 0; ww < WPP; ++ww) s2 += wpart[tid * WPP + ww];
            sqn_out[pt_base + tid] = s2;
        }
    }
}

// ---------------- feat = max over 16 row-blocks of gpart ----------------
__global__ void featmax_kernel(const float* __restrict__ gpart, float* __restrict__ feat) {
    int t = blockIdx.x * 256 + threadIdx.x;
    int b = t >> 10, d = t & 1023;
    float m = -FLT_MAX;
    for (int rb = 0; rb < 16; ++rb)
        m = fmaxf(m, gpart[(size_t)(b * 16 + rb) * 1024 + d]);
    feat[t] = m;
}

// ---------------- FC k-split: partials over 64-k chunks; W read exactly once ----------------
__global__ void fc_part_kernel(const float* __restrict__ in, const float* __restrict__ W,
                               float* __restrict__ part, int N) {
    __shared__ float sin_[16][64];
    __shared__ float red[3][16][64];
    int tid = threadIdx.x, lane = tid & 63, g = tid >> 6;
    int col = blockIdx.x * 64 + lane;
    int k0 = blockIdx.y * 64;
    for (int i = tid; i < 1024; i += 256)
        sin_[i >> 6][i & 63] = in[(i >> 6) * 1024 + k0 + (i & 63)];
    __syncthreads();
    float acc[16];
#pragma unroll
    for (int b = 0; b < 16; ++b) acc[b] = 0.f;
    int kk0 = g * 16;
#pragma unroll
    for (int k = kk0; k < kk0 + 16; ++k) {
        float wv = W[(size_t)(k0 + k) * N + col];
#pragma unroll
        for (int b = 0; b < 16; ++b) acc[b] = fmaf(sin_[b][k], wv, acc[b]);
    }
    if (g) {
#pragma unroll
        for (int b = 0; b < 16; ++b) red[g - 1][b][lane] = acc[b];
    }
    __syncthreads();
    if (g == 0) {
#pragma unroll
        for (int b = 0; b < 16; ++b) {
            float v = acc[b] + red[0][b][lane] + red[1][b][lane] + red[2][b][lane];
            part[((size_t)blockIdx.y * 16 + b) * N + col] = v;
        }
    }
}

__global__ void fc_reduce_kernel(const float* __restrict__ part, const float* __restrict__ bias,
                                 float* __restrict__ out, int N, int act) {
    int t = blockIdx.x * 256 + threadIdx.x;
    int b = t / N, col = t % N;
    float s = bias[col];
#pragma unroll
    for (int ks = 0; ks < 16; ++ks) s += part[((size_t)ks * 16 + b) * N + col];
    if (act) s = fmaxf(s, 0.f);
    out[(size_t)b * N + col] = s;
}

// ---------------- chamfer pass A ----------------
__launch_bounds__(256)
__global__ void chamferA_kernel(const float* __restrict__ coarse,
                                const float* __restrict__ pts,
                                float* __restrict__ pA) {
    __shared__ float spx[2048], spy[2048], spz[2048];
    __shared__ float red[4];
    int b = blockIdx.x, ch = blockIdx.y, tid = threadIdx.x;
    const float* pb = pts + (size_t)b * 6144;
    for (int i = tid; i < 2048; i += 256) {
        spx[i] = pb[i * 3]; spy[i] = pb[i * 3 + 1]; spz[i] = pb[i * 3 + 2];
    }
    __syncthreads();
    int q = ch * 32 + (tid >> 3);
    int oct = tid & 7;
    const float* cp = coarse + (size_t)b * 3072 + q * 3;
    float cx = cp[0], cy = cp[1], cz = cp[2];
    float mn0 = FLT_MAX, mn1 = FLT_MAX, mn2 = FLT_MAX, mn3 = FLT_MAX;
    int n0 = oct * 256;
    for (int n = n0; n < n0 + 256; n += 4) {
        float dx, dy, dz;
        dx = cx - spx[n];     dy = cy - spy[n];     dz = cz - spz[n];
        mn0 = fminf(mn0, fmaf(dx, dx, fmaf(dy, dy, dz * dz)));
        dx = cx - spx[n + 1]; dy = cy - spy[n + 1]; dz = cz - spz[n + 1];
        mn1 = fminf(mn1, fmaf(dx, dx, fmaf(dy, dy, dz * dz)));
        dx = cx - spx[n + 2]; dy = cy - spy[n + 2]; dz = cz - spz[n + 2];
        mn2 = fminf(mn2, fmaf(dx, dx, fmaf(dy, dy, dz * dz)));
        dx = cx - spx[n + 3]; dy = cy - spy[n + 3]; dz = cz - spz[n + 3];
        mn3 = fminf(mn3, fmaf(dx, dx, fmaf(dy, dy, dz * dz)));
    }
    float mn = fminf(fminf(mn0, mn1), fminf(mn2, mn3));
    mn = fminf(mn, __shfl_xor(mn, 1));
    mn = fminf(mn, __shfl_xor(mn, 2));
    mn = fminf(mn, __shfl_xor(mn, 4));
    float s = (oct == 0) ? mn : 0.f;
#pragma unroll
    for (int off = 32; off > 0; off >>= 1) s += __shfl_down(s, off);
    int w = tid >> 6, lane = tid & 63;
    if (lane == 0) red[w] = s;
    __syncthreads();
    if (tid == 0) pA[b * 32 + ch] = red[0] + red[1] + red[2] + red[3];
}

// ---------------- chamfer pass B ----------------
__launch_bounds__(256)
__global__ void chamferB_kernel(const float* __restrict__ coarse,
                                const float* __restrict__ pts,
                                float* __restrict__ pB) {
    __shared__ float scx[1024], scy[1024], scz[1024];
    __shared__ float red[4];
    int b = blockIdx.x, ch = blockIdx.y, tid = threadIdx.x;
    const float* cb = coarse + (size_t)b * 3072;
    for (int i = tid; i < 1024; i += 256) {
        scx[i] = cb[i * 3]; scy[i] = cb[i * 3 + 1]; scz[i] = cb[i * 3 + 2];
    }
    __syncthreads();
    int p = ch * 64 + (tid >> 2);
    int quad = tid & 3;
    const float* pp = pts + (size_t)b * 6144 + p * 3;
    float px = pp[0], py = pp[1], pz = pp[2];
    float mn0 = FLT_MAX, mn1 = FLT_MAX, mn2 = FLT_MAX, mn3 = FLT_MAX;
    int m0 = quad * 256;
    for (int m = m0; m < m0 + 256; m += 4) {
        float dx, dy, dz;
        dx = px - scx[m];     dy = py - scy[m];     dz = pz - scz[m];
        mn0 = fminf(mn0, fmaf(dx, dx, fmaf(dy, dy, dz * dz)));
        dx = px - scx[m + 1]; dy = py - scy[m + 1]; dz = pz - scz[m + 1];
        mn1 = fminf(mn1, fmaf(dx, dx, fmaf(dy, dy, dz * dz)));
        dx = px - scx[m + 2]; dy = py - scy[m + 2]; dz = pz - scz[m + 2];
        mn2 = fminf(mn2, fmaf(dx, dx, fmaf(dy, dy, dz * dz)));
        dx = px - scx[m + 3]; dy = py - scy[m + 3]; dz = pz - scz[m + 3];
        mn3 = fminf(mn3, fmaf(dx, dx, fmaf(dy, dy, dz * dz)));
    }
    float mn = fminf(fminf(mn0, mn1), fminf(mn2, mn3));
    mn = fminf(mn, __shfl_xor(mn, 1));
    mn = fminf(mn, __shfl_xor(mn, 2));
    float s = (quad == 0) ? mn : 0.f;
#pragma unroll
    for (int off = 32; off > 0; off >>= 1) s += __shfl_down(s, off);
    int w = tid >> 6, lane = tid & 63;
    if (lane == 0) red[w] = s;
    __syncthreads();
    if (tid == 0) pB[b * 32 + ch] = red[0] + red[1] + red[2] + red[3];
}

__global__ void loss_kernel(const float* __restrict__ pA, const float* __restrict__ pB,
                            float* __restrict__ out) {
    __shared__ float rA[4], rB[4];
    int tid = threadIdx.x;
    float a = pA[tid] + pA[tid + 256];
    float b = pB[tid] + pB[tid + 256];
#pragma unroll
    for (int off = 32; off > 0; off >>= 1) {
        a += __shfl_down(a, off);
        b += __shfl_down(b, off);
    }
    int w = tid >> 6, lane = tid & 63;
    if (lane == 0) { rA[w] = a; rB[w] = b; }
    __syncthreads();
    if (tid == 0)
        out[0] = (rA[0] + rA[1] + rA[2] + rA[3]) / (16.f * 1024.f)
               + (rB[0] + rB[1] + rB[2] + rB[3]) / (16.f * 2048.f);
}

extern "C" void kernel_launch(void* const* d_in, const int* in_sizes, int n_in,
                              void* d_out, int out_size, void* d_ws, size_t ws_size,
                              hipStream_t stream) {
    const float* corrupted = (const float*)d_in[0];
    const float* pts = (const float*)d_in[1];
    const float* w1 = (const float*)d_in[2];   const float* b1 = (const float*)d_in[3];
    const float* w2 = (const float*)d_in[4];   const float* b2 = (const float*)d_in[5];
    const float* w3 = (const float*)d_in[6];   const float* b3 = (const float*)d_in[7];
    const float* w4 = (const float*)d_in[8];   const float* b4 = (const float*)d_in[9];
    const float* w5 = (const float*)d_in[10];  const float* b5 = (const float*)d_in[11];
    const float* fw1 = (const float*)d_in[12]; const float* fb1 = (const float*)d_in[13];
    const float* fw2 = (const float*)d_in[14]; const float* fb2 = (const float*)d_in[15];
    const float* fw3 = (const float*)d_in[16]; const float* fb3 = (const float*)d_in[17];
    float* out = (float*)d_out;

    char* ws = (char*)d_ws;
    u16*   cathi  = (u16*)(ws);                   // [32768][512] bf16 hi   32 MB
    u16*   catlo  = (u16*)(ws + 33554432);        // [32768][512] bf16 lo   32 MB
    float* ut     = (float*)(ws + 67108864);      // 64 MB (aliased dist/fcpart)
    u16*   dist   = (u16*)ut;                     // [8][2048][2048] u16 keys
    float* fcpart = ut;
    int*   idx    = (int*)  (ws + 134217728);     // [32768][20]
    float* sqn    = (float*)(ws + 136839168);     // [32768]
    u16*   Bw5h   = (u16*)(ws + 136970240);       // 1 MB
    u16*   Bw5l   = (u16*)(ws + 138018816);       // 1 MB
    float* bt34   = (float*)(ws + 139067392);
    float* bt2    = bt34;
    float* bt3    = bt34 + 128;
    float* bt4    = bt34 + 384;
    char*  G      = ws + 139071488;               // gpart region (1 MB), dual-use
    u16*   Be2h   = (u16*)(G);
    u16*   Be2l   = (u16*)(G + 16384);
    u16*   Be3h   = (u16*)(G + 32768);
    u16*   Be3l   = (u16*)(G + 65536);
    u16*   Be4h   = (u16*)(G + 98304);
    u16*   Be4l   = (u16*)(G + 229376);
    float* wtf    = (float*)(G + 360448);
    float* bt1    = (float*)(G + 362496);
    float* gpart  = (float*)G;
    float* feat   = (float*)(ws + 140120064);
    float* h1     = (float*)(ws + 140185600);
    float* h2     = (float*)(ws + 140251136);
    float* coarse = (float*)(ws + 140316672);
    float* pA     = (float*)(ws + 140513280);
    float* pB     = (float*)(ws + 140515328);

    // ---- one batched prep for all weights ----
    prep_all_kernel<<<2406, 256, 0, stream>>>(w1, b1, w2, b2, w3, b3, w4, b4, w5,
                                              Bw5h, Bw5l, Be2h, Be2l, Be3h, Be3l,
                                              Be4h, Be4l, bt2, bt3, bt4, wtf, bt1);

    // ---- conv1 ----
    select3_kernel<<<2048, 256, 0, stream>>>(corrupted, idx);
    conv1_kernel<<<16384, 256, 0, stream>>>(corrupted, wtf, bt1, ut);
    gather_max_kernel<64><<<8192, 256, 0, stream>>>(ut, idx, cathi, catlo, 0, sqn);

    // ---- convs 2-4: symmetric hi-only MFMA gram (u16 keys, 2 groups of z=8) ----
    auto conv = [&](int coloff, int C, int Cout, const u16* Beh, const u16* Bel,
                    const float* btp, int colout, bool needNextSqn) {
        int N2 = 2 * Cout;
        for (int g = 0; g < 2; ++g) {
            size_t off = ((size_t)g * 8 * N_) * 512 + coloff;
            mfma_gemm<3><<<dim3(136, 1, 8), 256, 0, stream>>>(
                cathi + off, (long long)N_ * 512, 512,
                cathi + off, catlo + off, (long long)N_ * 512, 512,
                sqn + (size_t)g * 8 * N_, N_,
                (float*)dist, (long long)(N_ * N_ / 2), N_, C);
            select_kernel<<<2048, 256, 0, stream>>>(dist, idx + (size_t)g * 8 * N_ * KNN);
        }
        mfma_gemm<0><<<dim3(256, N2 / 128, 1), 256, 0, stream>>>(
            cathi + coloff, 0, 512,
            Beh, Bel, 0, C,
            btp, 0,
            ut, 0, N2, C);
        float* sq = needNextSqn ? sqn : nullptr;
        if (Cout == 64)       gather_max_kernel<64><<<8192, 256, 0, stream>>>(ut, idx, cathi, catlo, colout, sq);
        else if (Cout == 128) gather_max_kernel<128><<<16384, 256, 0, stream>>>(ut, idx, cathi, catlo, colout, sq);
        else                  gather_max_kernel<256><<<32768, 256, 0, stream>>>(ut, idx, cathi, catlo, colout, sq);
    };
    conv(0, 64, 64, Be2h, Be2l, bt2, 64, true);
    conv(64, 64, 128, Be3h, Be3l, bt3, 128, true);
    conv(128, 128, 256, Be4h, Be4l, bt4, 256, false);

    // ---- w5 + leaky + max over N (fused epilogue, split-2) ----
    mfma_gemm<1><<<dim3(256, 8, 1), 256, 0, stream>>>(
        cathi, 0, 512,
        Bw5h, Bw5l, 0, 512,
        b5, 0,
        gpart, 0, 1024, 512);
    featmax_kernel<<<64, 256, 0, stream>>>(gpart, feat);

    // ---- FCs: k-split partials + reduce (deterministic) ----
    fc_part_kernel<<<dim3(16, 16), 256, 0, stream>>>(feat, fw1, fcpart, 1024);
    fc_reduce_kernel<<<64, 256, 0, stream>>>(fcpart, fb1, h1, 1024, 1);
    fc_part_kernel<<<dim3(16, 16), 256, 0, stream>>>(h1, fw2, fcpart, 1024);
    fc_reduce_kernel<<<64, 256, 0, stream>>>(fcpart, fb2, h2, 1024, 1);
    fc_part_kernel<<<dim3(48, 16), 256, 0, stream>>>(h2, fw3, fcpart, 3072);
    fc_reduce_kernel<<<192, 256, 0, stream>>>(fcpart, fb3, coarse, 3072, 0);

    chamferA_kernel<<<dim3(16, 32), 256, 0, stream>>>(coarse, pts, pA);
    chamferB_kernel<<<dim3(16, 32), 256, 0, stream>>>(coarse, pts, pB);
    loss_kernel<<<1, 256, 0, stream>>>(pA, pB, out);
}

// Round 18
// 571.891 us; speedup vs baseline: 1.1330x; 1.1330x over previous
//
#include <hip/hip_runtime.h>
#include <float.h>

#define B_ 16
#define N_ 2048
#define KNN 20

typedef unsigned short u16;
typedef __attribute__((ext_vector_type(8))) short bf16x8;
typedef __attribute__((ext_vector_type(4))) float f32x4;

typedef const __attribute__((address_space(1))) unsigned gas_t;
typedef __attribute__((address_space(3))) unsigned las_t;

__device__ inline u16 bfhi(float v) {
    union { float f; unsigned u; } x; x.f = v;
    unsigned r = x.u + 0x7FFFu + ((x.u >> 16) & 1u);
    return (u16)(r >> 16);
}
__device__ inline u16 bflo(float v, u16 h) {
    union { unsigned u; float f; } y; y.u = ((unsigned)h) << 16;
    return bfhi(v - y.f);
}
__device__ inline unsigned fkey(float v) {
    union { float f; unsigned u; } x;
    x.f = fmaxf(v, 0.f);
    return x.u & 0x7FFFFFFFu;
}
__device__ inline u16 fkey16(float v) { return (u16)(fkey(v) >> 15); }
__device__ inline unsigned umin_(unsigned a, unsigned b) { return a < b ? a : b; }

// payload (element index) encoding per keys-per-lane layout
template <int MODE>
__device__ inline unsigned payof(int i, int lane) {
    if (MODE == 0) return ((unsigned)(i >> 2) << 8) + (unsigned)lane * 4u + (unsigned)(i & 3);
    else           return ((unsigned)(i >> 3) << 9) + (unsigned)lane * 8u + (unsigned)(i & 7);
}

// ---------------- bitonic sort across 64 lanes (ascending by key) ----------------
template <bool P>
__device__ inline void bitonic64(unsigned& key, unsigned& pay, int lane) {
#pragma unroll
    for (int k = 2; k <= 64; k <<= 1) {
#pragma unroll
        for (int j = k >> 1; j > 0; j >>= 1) {
            unsigned ok = __shfl_xor(key, j);
            unsigned op = P ? __shfl_xor(pay, j) : 0u;
            bool up = ((lane & k) == 0);
            bool lower = ((lane & j) == 0);
            bool takeOther = (up == lower) ? (ok < key) : (ok > key);
            if (takeOther) { key = ok; if (P) pay = op; }
        }
    }
}

// ---------------- top-20-smallest via threshold filter (round-15 form) ----------------
template <int MODE>
__device__ inline void select20(const unsigned* kr, int lane,
                                unsigned* klist, unsigned* ilist,
                                int* __restrict__ outIdx) {
    unsigned lm = kr[0];
#pragma unroll
    for (int i = 1; i < 32; ++i) lm = umin_(lm, kr[i]);
    unsigned dummy = 0, sk = lm;
    bitonic64<false>(sk, dummy, lane);
    unsigned S = __shfl(sk, 19);
    unsigned c = 0;
#pragma unroll
    for (int i = 0; i < 32; ++i) c += (kr[i] <= S) ? 1u : 0u;
    unsigned incl = c;
#pragma unroll
    for (int d = 1; d < 64; d <<= 1) {
        unsigned t = __shfl_up(incl, d);
        if (lane >= d) incl += t;
    }
    unsigned stot = __shfl(incl, 63);
    unsigned pos = incl - c;
    klist[lane] = 0xFFFFFFFFu;
    __syncthreads();
#pragma unroll
    for (int i = 0; i < 32; ++i) {
        if (kr[i] <= S) {
            if (pos < 64u) {
                klist[pos] = kr[i];
                ilist[pos] = payof<MODE>(i, lane);
            }
            ++pos;
        }
    }
    __syncthreads();
    if (stot <= 64u) {
        unsigned key = klist[lane], pay = ilist[lane];
        bitonic64<true>(key, pay, lane);
        if (lane < KNN) outIdx[lane] = (int)pay;
    } else {
        unsigned taken = 0;
        for (int it = 0; it < KNN; ++it) {
            unsigned bk = 0xFFFFFFFFu; int bi = 0;
#pragma unroll
            for (int i = 0; i < 32; ++i) {
                bool better = (((taken >> i) & 1u) == 0u) && (kr[i] < bk);
                if (better) { bk = kr[i]; bi = i; }
            }
            unsigned bl = (unsigned)lane;
#pragma unroll
            for (int off = 32; off > 0; off >>= 1) {
                unsigned ok = __shfl_down(bk, off);
                unsigned ol = __shfl_down(bl, off);
                int oi = __shfl_down(bi, off);
                if (ok < bk) { bk = ok; bl = ol; bi = oi; }
            }
            bl = __shfl(bl, 0); bi = __shfl(bi, 0);
            if (lane == (int)bl) taken |= (1u << bi);
            if (lane == 0) outIdx[it] = (int)payof<MODE>(bi, (int)bl);
        }
    }
}

// select for convs 2-4: reads precomputed u16 keys (8 keys/lane/chunk)
__launch_bounds__(256)
__global__ void select_kernel(const u16* __restrict__ dist, int* __restrict__ idx_out) {
    __shared__ unsigned kl[4][64], il[4][64];
    int tid = threadIdx.x, w = tid >> 6, lane = tid & 63;
    size_t q = (size_t)blockIdx.x * 4 + w;
    const u16* src = dist + q * N_;
    unsigned kr[32];
#pragma unroll
    for (int j = 0; j < 4; ++j) {
        uint4 v = *(const uint4*)&src[j * 512 + lane * 8];
        const unsigned* pw = (const unsigned*)&v;
#pragma unroll
        for (int e = 0; e < 4; ++e) {
            kr[j * 8 + 2 * e]     = pw[e] & 0xFFFFu;
            kr[j * 8 + 2 * e + 1] = pw[e] >> 16;
        }
    }
    select20<1>(kr, lane, kl[w], il[w], idx_out + q * KNN);
}

// select for conv1: distances straight from 3-D coords; 16 queries per block
__launch_bounds__(256)
__global__ void select3_kernel(const float* __restrict__ x, int* __restrict__ idx_out) {
    __shared__ __align__(16) float cx[N_], cy[N_], cz[N_];
    __shared__ unsigned kl[4][64], il[4][64];
    int tid = threadIdx.x, blk = blockIdx.x;
    int b = blk >> 7, n0 = (blk & 127) * 16;
    for (int i = tid; i < N_; i += 256) {
        const float* p = x + (size_t)(b * N_ + i) * 3;
        cx[i] = p[0]; cy[i] = p[1]; cz[i] = p[2];
    }
    __syncthreads();
    int w = tid >> 6, lane = tid & 63;
    for (int r = 0; r < 4; ++r) {
        int q = n0 + r * 4 + w;
        float qx = cx[q], qy = cy[q], qz = cz[q];
        unsigned kr[32];
#pragma unroll
        for (int j = 0; j < 8; ++j) {
            float4 vx = *(const float4*)&cx[j * 256 + lane * 4];
            float4 vy = *(const float4*)&cy[j * 256 + lane * 4];
            float4 vz = *(const float4*)&cz[j * 256 + lane * 4];
            float dx, dy, dz;
            dx = qx - vx.x; dy = qy - vy.x; dz = qz - vz.x;
            kr[j * 4 + 0] = fkey(fmaf(dx, dx, fmaf(dy, dy, dz * dz)));
            dx = qx - vx.y; dy = qy - vy.y; dz = qz - vz.y;
            kr[j * 4 + 1] = fkey(fmaf(dx, dx, fmaf(dy, dy, dz * dz)));
            dx = qx - vx.z; dy = qy - vy.z; dz = qz - vz.z;
            kr[j * 4 + 2] = fkey(fmaf(dx, dx, fmaf(dy, dy, dz * dz)));
            dx = qx - vx.w; dy = qy - vy.w; dz = qz - vz.w;
            kr[j * 4 + 3] = fkey(fmaf(dx, dx, fmaf(dy, dy, dz * dz)));
        }
        select20<0>(kr, lane, kl[w], il[w], idx_out + ((size_t)(b * N_ + q)) * KNN);
    }
}

// ---------------- batched weight prep: w5 + 3 edge-Bs + conv1 wt + biases ----------------
__global__ void prep_all_kernel(const float* __restrict__ w1, const float* __restrict__ b1,
                                const float* __restrict__ w2, const float* __restrict__ b2,
                                const float* __restrict__ w3, const float* __restrict__ b3,
                                const float* __restrict__ w4, const float* __restrict__ b4,
                                const float* __restrict__ w5,
                                u16* __restrict__ Bw5h, u16* __restrict__ Bw5l,
                                u16* __restrict__ Be2h, u16* __restrict__ Be2l,
                                u16* __restrict__ Be3h, u16* __restrict__ Be3l,
                                u16* __restrict__ Be4h, u16* __restrict__ Be4l,
                                float* __restrict__ bt2, float* __restrict__ bt3,
                                float* __restrict__ bt4,
                                float* __restrict__ wtf, float* __restrict__ bt1) {
    int t = blockIdx.x * 256 + threadIdx.x;
    if (t < 524288) {
        int n = t / 512, k = t % 512;
        float v = w5[(size_t)k * 1024 + n];
        u16 h = bfhi(v);
        Bw5h[t] = h; Bw5l[t] = bflo(v, h);
    } else if (t < 532480) {
        int e = t - 524288;
        int d = e / 64, c = e % 64;
        float v = (d < 64) ? w2[c * 64 + d] : (w2[(64 + c) * 64 + (d - 64)] - w2[c * 64 + (d - 64)]);
        u16 h = bfhi(v);
        Be2h[e] = h; Be2l[e] = bflo(v, h);
    } else if (t < 548864) {
        int e = t - 532480;
        int d = e / 64, c = e % 64;
        float v = (d < 128) ? w3[c * 128 + d] : (w3[(64 + c) * 128 + (d - 128)] - w3[c * 128 + (d - 128)]);
        u16 h = bfhi(v);
        Be3h[e] = h; Be3l[e] = bflo(v, h);
    } else if (t < 614400) {
        int e = t - 548864;
        int d = e / 128, c = e % 128;
        float v = (d < 256) ? w4[c * 256 + d] : (w4[(128 + c) * 256 + (d - 256)] - w4[c * 256 + (d - 256)]);
        u16 h = bfhi(v);
        Be4h[e] = h; Be4l[e] = bflo(v, h);
    } else if (t < 614528) {
        int e = t - 614400;
        bt2[e] = (e < 64) ? 0.f : b2[e - 64];
    } else if (t < 614784) {
        int e = t - 614528;
        bt3[e] = (e < 128) ? 0.f : b3[e - 128];
    } else if (t < 615296) {
        int e = t - 614784;
        bt4[e] = (e < 256) ? 0.f : b4[e - 256];
    } else if (t < 615680) {
        int e = t - 615296;
        int c = e / 128, d = e % 128;
        float v = (d < 64) ? w1[c * 64 + d] : (w1[(3 + c) * 64 + (d - 64)] - w1[c * 64 + (d - 64)]);
        wtf[e] = v;
    } else if (t < 615808) {
        int e = t - 615680;
        bt1[e] = (e < 64) ? 0.f : b1[e - 64];
    }
}

// ---------------- bf16 MFMA GEMM, 128x128 tile, 4 waves (2x2) ----------------
// EPI 0/1: SPLIT-2 product (aH*bH + aH*bL), XCD-chunked mapping.
// EPI=3: u16 dist keys, HI-ONLY product (1 MFMA), symmetric upper-triangle grid.
template <int EPI>
__launch_bounds__(256, 2)
__global__ void mfma_gemm(const u16* __restrict__ Ah,
                          long long aZ, int lda,
                          const u16* __restrict__ Bh, const u16* __restrict__ Bl,
                          long long bZ, int ldb,
                          const float* __restrict__ ep, long long epZ,
                          float* __restrict__ out, long long outZ, int ldo,
                          int K) {
    __shared__ __align__(16) char smem[73728];
    u16* AsH = (u16*)(smem);
    u16* BsH = (u16*)(smem + 16384);
    u16* BsL = (u16*)(smem + 32768);
    u16 (*LTs)[136] = (u16(*)[136])(smem);
    __shared__ float red[2][128];
    int tid = threadIdx.x;
    int m0, n0, mt = 0;
    if (EPI == 3) {
        int t = blockIdx.x, rem = 16, bi = 0;
        while (t >= rem) { t -= rem; ++bi; --rem; }
        m0 = bi * 128; n0 = (bi + t) * 128;
    } else {
        int MT = gridDim.x, NT = gridDim.y;
        int f = blockIdx.x + blockIdx.y * MT;
        int xcd = f & 7, s = f >> 3;
        int sm = s / NT;
        int nt = s - sm * NT;
        mt = xcd * (MT >> 3) + sm;
        m0 = mt * 128; n0 = nt * 128;
    }
    int z = blockIdx.z;
    const u16* ah = Ah + (size_t)z * aZ;
    const u16* bh = Bh + (size_t)z * bZ;
    const u16* bl = Bl + (size_t)z * bZ;
    const float* epz = ep + (size_t)z * epZ;
    float* op = out + (size_t)z * outZ;

    int wid = tid >> 6, lane = tid & 63;
    int wm = wid >> 1, wn = wid & 1;
    int l15 = lane & 15, l4 = lane >> 4;
    int lrow8 = lane >> 3;
    int lg = lane & 7;

    f32x4 acc[4][4];
#pragma unroll
    for (int i = 0; i < 4; ++i)
#pragma unroll
        for (int j = 0; j < 4; ++j) acc[i][j] = (f32x4){0.f, 0.f, 0.f, 0.f};

    for (int k0 = 0; k0 < K; k0 += 64) {
        if (k0) __syncthreads();
#pragma unroll
        for (int ch = 0; ch < 4; ++ch) {
            int row = wid * 32 + ch * 8 + lrow8;
            int gsrc = lg ^ (row & 7);
            unsigned ldsoff = (unsigned)(wid * 32 + ch * 8) * 64;
            size_t ga = (size_t)(m0 + row) * lda + k0 + gsrc * 8;
            size_t gb = (size_t)(n0 + row) * ldb + k0 + gsrc * 8;
            __builtin_amdgcn_global_load_lds((gas_t*)(ah + ga), (las_t*)(AsH + ldsoff), 16, 0, 0);
            __builtin_amdgcn_global_load_lds((gas_t*)(bh + gb), (las_t*)(BsH + ldsoff), 16, 0, 0);
            if (EPI != 3)
                __builtin_amdgcn_global_load_lds((gas_t*)(bl + gb), (las_t*)(BsL + ldsoff), 16, 0, 0);
        }
        __syncthreads();
#pragma unroll
        for (int kk = 0; kk < 2; ++kk) {
            int ko_g = kk * 4 + l4;
            bf16x8 aH[4], bH[4], bL[4];
#pragma unroll
            for (int i = 0; i < 4; ++i) {
                int ra = wm * 64 + i * 16 + l15;
                int oa = ra * 64 + ((ko_g ^ (ra & 7)) << 3);
                aH[i] = *(const bf16x8*)&AsH[oa];
                int rb = wn * 64 + i * 16 + l15;
                int ob = rb * 64 + ((ko_g ^ (rb & 7)) << 3);
                bH[i] = *(const bf16x8*)&BsH[ob];
                if (EPI != 3) bL[i] = *(const bf16x8*)&BsL[ob];
            }
#pragma unroll
            for (int i = 0; i < 4; ++i)
#pragma unroll
                for (int j = 0; j < 4; ++j) {
                    acc[i][j] = __builtin_amdgcn_mfma_f32_16x16x32_bf16(aH[i], bH[j], acc[i][j], 0, 0, 0);
                    if (EPI != 3)
                        acc[i][j] = __builtin_amdgcn_mfma_f32_16x16x32_bf16(aH[i], bL[j], acc[i][j], 0, 0, 0);
                }
        }
    }

    if (EPI == 0) {
#pragma unroll
        for (int i = 0; i < 4; ++i)
#pragma unroll
            for (int r = 0; r < 4; ++r) {
                int grow = m0 + wm * 64 + i * 16 + l4 * 4 + r;
#pragma unroll
                for (int j = 0; j < 4; ++j) {
                    int col = n0 + wn * 64 + j * 16 + l15;
                    op[(size_t)grow * ldo + col] = acc[i][j][r] + epz[col];
                }
            }
    } else if (EPI == 1) {
        float pm[4];
#pragma unroll
        for (int j = 0; j < 4; ++j) {
            float v = -FLT_MAX;
#pragma unroll
            for (int i = 0; i < 4; ++i)
#pragma unroll
                for (int r = 0; r < 4; ++r) v = fmaxf(v, acc[i][j][r]);
            v = fmaxf(v, __shfl_xor(v, 16));
            v = fmaxf(v, __shfl_xor(v, 32));
            pm[j] = v;
        }
        if (l4 == 0) {
#pragma unroll
            for (int j = 0; j < 4; ++j) red[wm][wn * 64 + j * 16 + l15] = pm[j];
        }
        __syncthreads();
        if (tid < 128) {
            float v = fmaxf(red[0][tid], red[1][tid]) + epz[n0 + tid];
            v = (v > 0.f) ? v : 0.2f * v;
            op[(size_t)mt * ldo + n0 + tid] = v;
        }
    } else {
        u16* opu = (u16*)op;
#pragma unroll
        for (int i = 0; i < 4; ++i)
#pragma unroll
            for (int r = 0; r < 4; ++r) {
                int grow = m0 + wm * 64 + i * 16 + l4 * 4 + r;
                float sm = epz[grow];
#pragma unroll
                for (int j = 0; j < 4; ++j) {
                    int col = n0 + wn * 64 + j * 16 + l15;
                    opu[(size_t)grow * ldo + col] = fkey16(sm + epz[col] - 2.f * acc[i][j][r]);
                }
            }
        if (m0 != n0) {
            __syncthreads();
#pragma unroll
            for (int i = 0; i < 4; ++i)
#pragma unroll
                for (int j = 0; j < 4; ++j) {
                    int colL  = wn * 64 + j * 16 + l15;
                    int growL = wm * 64 + i * 16 + l4 * 4;
                    unsigned k0v = fkey16(epz[m0 + growL + 0] + epz[n0 + colL] - 2.f * acc[i][j][0]);
                    unsigned k1v = fkey16(epz[m0 + growL + 1] + epz[n0 + colL] - 2.f * acc[i][j][1]);
                    unsigned k2v = fkey16(epz[m0 + growL + 2] + epz[n0 + colL] - 2.f * acc[i][j][2]);
                    unsigned k3v = fkey16(epz[m0 + growL + 3] + epz[n0 + colL] - 2.f * acc[i][j][3]);
                    uint2 pk;
                    pk.x = k0v | (k1v << 16);
                    pk.y = k2v | (k3v << 16);
                    *(uint2*)&LTs[colL][growL] = pk;
                }
            __syncthreads();
            for (int rr0 = 0; rr0 < 128; rr0 += 8) {
                int rr = rr0 + (tid >> 5), cc = (tid & 31) * 4;
                uint2 v = *(const uint2*)&LTs[rr][cc];
                *(uint2*)&opu[(size_t)(n0 + rr) * ldo + m0 + cc] = v;
            }
        }
    }
}

// ---------------- conv1 direct GEMM (K=3) ----------------
__global__ void conv1_kernel(const float* __restrict__ x, const float* __restrict__ wt,
                             const float* __restrict__ bt, float* __restrict__ ut) {
    __shared__ float sw[3][128], sb[128];
    int tid = threadIdx.x;
    if (tid < 128) { sw[0][tid] = wt[tid]; sw[1][tid] = wt[128 + tid]; }
    else { int d = tid - 128; sw[2][d] = wt[256 + d]; sb[d] = bt[d]; }
    __syncthreads();
    int t = blockIdx.x * 256 + tid;
    int m = t >> 7, d = t & 127;
    const float* xm = x + (size_t)m * 3;
    float v = sb[d];
    v = fmaf(xm[0], sw[0][d], v);
    v = fmaf(xm[1], sw[1][d], v);
    v = fmaf(xm[2], sw[2][d], v);
    ut[(size_t)m * 128 + d] = v;
}

// ---------------- gather + leaky + max over k + fused next-conv sqnorm ----------------
template <int COUT>
__global__ void gather_max_kernel(const float* __restrict__ ut,
                                  const int* __restrict__ idx,
                                  u16* __restrict__ cathi, u16* __restrict__ catlo,
                                  int coloff, float* __restrict__ sqn_out) {
    const int P = 256 / COUT;
    int tid = threadIdx.x;
    int p = tid / COUT, d = tid % COUT;
    int nb = gridDim.x;
    int i = blockIdx.x;
    int half = (i >= (nb >> 1)) ? 1 : 0;
    int ii = i - half * (nb >> 1);
    int b = half * 8 + (ii & 7);
    int within = ii >> 3;
    int pt_base = b * 2048 + within * P;
    int pt = pt_base + p;
    int n = pt & 2047;
    __shared__ int sidx[P][KNN];
    __shared__ float wpart[4];
    for (int q = tid; q < P * KNN; q += 256) {
        int pp = q / KNN, kk = q % KNN;
        sidx[pp][kk] = idx[(size_t)(pt_base + pp) * KNN + kk];
    }
    __syncthreads();
    const int N2 = 2 * COUT;
    const float* utb = ut + (size_t)b * N_ * N2;
    float tval = utb[(size_t)n * N2 + COUT + d];
    float acc = -FLT_MAX;
#pragma unroll
    for (int k = 0; k < KNN; k++) {
        int j = __builtin_amdgcn_readfirstlane(sidx[p][k]);
        const float* rp = utb + (size_t)j * N2;
        float s = rp[d] + tval;
        s = (s > 0.f) ? s : 0.2f * s;
        acc = fmaxf(acc, s);
    }
    u16 h = bfhi(acc);
    u16 l = bflo(acc, h);
    cathi[(size_t)pt * 512 + coloff + d] = h;
    catlo[(size_t)pt * 512 + coloff + d] = l;
    if (sqn_out) {
        union { unsigned u; float f; } va, vb;
        va.u = ((unsigned)h) << 16; vb.u = ((unsigned)l) << 16;
        float v = va.f + vb.f;
        float sq = v * v;
#pragma unroll
        for (int off = 1; off < 64; off <<= 1) sq += __shfl_xor(sq, off);
        int wid = tid >> 6, lane = tid & 63;
        if (lane == 0) wpart[wid] = sq;
        __syncthreads();
        const int WPP = COUT / 64;
        if (tid < P) {
            float s2 = 0.f;
#pragma unroll
            for (int ww = 0; ww < WPP; ++ww) s2 += wpart[tid * WPP + ww];
            sqn_out[pt_base + tid] = s2;
        }
    }
}

// ---------------- feat = max over 16 row-blocks of gpart ----------------
__global__ void featmax_kernel(const float* __restrict__ gpart, float* __restrict__ feat) {
    int t = blockIdx.x * 256 + threadIdx.x;
    int b = t >> 10, d = t & 1023;
    float m = -FLT_MAX;
    for (int rb = 0; rb < 16; ++rb)
        m = fmaxf(m, gpart[(size_t)(b * 16 + rb) * 1024 + d]);
    feat[t] = m;
}

// ---------------- FC k-split: partials over 64-k chunks; W read exactly once ----------------
__global__ void fc_part_kernel(const float* __restrict__ in, const float* __restrict__ W,
                               float* __restrict__ part, int N) {
    __shared__ float sin_[16][64];
    __shared__ float red[3][16][64];
    int tid = threadIdx.x, lane = tid & 63, g = tid >> 6;
    int col = blockIdx.x * 64 + lane;
    int k0 = blockIdx.y * 64;
    for (int i = tid; i < 1024; i += 256)
        sin_[i >> 6][i & 63] = in[(i >> 6) * 1024 + k0 + (i & 63)];
    __syncthreads();
    float acc[16];
#pragma unroll
    for (int b = 0; b < 16; ++b) acc[b] = 0.f;
    int kk0 = g * 16;
#pragma unroll
    for (int k = kk0; k < kk0 + 16; ++k) {
        float wv = W[(size_t)(k0 + k) * N + col];
#pragma unroll
        for (int b = 0; b < 16; ++b) acc[b] = fmaf(sin_[b][k], wv, acc[b]);
    }
    if (g) {
#pragma unroll
        for (int b = 0; b < 16; ++b) red[g - 1][b][lane] = acc[b];
    }
    __syncthreads();
    if (g == 0) {
#pragma unroll
        for (int b = 0; b < 16; ++b) {
            float v = acc[b] + red[0][b][lane] + red[1][b][lane] + red[2][b][lane];
            part[((size_t)blockIdx.y * 16 + b) * N + col] = v;
        }
    }
}

__global__ void fc_reduce_kernel(const float* __restrict__ part, const float* __restrict__ bias,
                                 float* __restrict__ out, int N, int act) {
    int t = blockIdx.x * 256 + threadIdx.x;
    int b = t / N, col = t % N;
    float s = bias[col];
#pragma unroll
    for (int ks = 0; ks < 16; ++ks) s += part[((size_t)ks * 16 + b) * N + col];
    if (act) s = fmaxf(s, 0.f);
    out[(size_t)b * N + col] = s;
}

// ---------------- chamfer pass A ----------------
__launch_bounds__(256)
__global__ void chamferA_kernel(const float* __restrict__ coarse,
                                const float* __restrict__ pts,
                                float* __restrict__ pA) {
    __shared__ float spx[2048], spy[2048], spz[2048];
    __shared__ float red[4];
    int b = blockIdx.x, ch = blockIdx.y, tid = threadIdx.x;
    const float* pb = pts + (size_t)b * 6144;
    for (int i = tid; i < 2048; i += 256) {
        spx[i] = pb[i * 3]; spy[i] = pb[i * 3 + 1]; spz[i] = pb[i * 3 + 2];
    }
    __syncthreads();
    int q = ch * 32 + (tid >> 3);
    int oct = tid & 7;
    const float* cp = coarse + (size_t)b * 3072 + q * 3;
    float cx = cp[0], cy = cp[1], cz = cp[2];
    float mn0 = FLT_MAX, mn1 = FLT_MAX, mn2 = FLT_MAX, mn3 = FLT_MAX;
    int n0 = oct * 256;
    for (int n = n0; n < n0 + 256; n += 4) {
        float dx, dy, dz;
        dx = cx - spx[n];     dy = cy - spy[n];     dz = cz - spz[n];
        mn0 = fminf(mn0, fmaf(dx, dx, fmaf(dy, dy, dz * dz)));
        dx = cx - spx[n + 1]; dy = cy - spy[n + 1]; dz = cz - spz[n + 1];
        mn1 = fminf(mn1, fmaf(dx, dx, fmaf(dy, dy, dz * dz)));
        dx = cx - spx[n + 2]; dy = cy - spy[n + 2]; dz = cz - spz[n + 2];
        mn2 = fminf(mn2, fmaf(dx, dx, fmaf(dy, dy, dz * dz)));
        dx = cx - spx[n + 3]; dy = cy - spy[n + 3]; dz = cz - spz[n + 3];
        mn3 = fminf(mn3, fmaf(dx, dx, fmaf(dy, dy, dz * dz)));
    }
    float mn = fminf(fminf(mn0, mn1), fminf(mn2, mn3));
    mn = fminf(mn, __shfl_xor(mn, 1));
    mn = fminf(mn, __shfl_xor(mn, 2));
    mn = fminf(mn, __shfl_xor(mn, 4));
    float s = (oct == 0) ? mn : 0.f;
#pragma unroll
    for (int off = 32; off > 0; off >>= 1) s += __shfl_down(s, off);
    int w = tid >> 6, lane = tid & 63;
    if (lane == 0) red[w] = s;
    __syncthreads();
    if (tid == 0) pA[b * 32 + ch] = red[0] + red[1] + red[2] + red[3];
}

// ---------------- chamfer pass B ----------------
__launch_bounds__(256)
__global__ void chamferB_kernel(const float* __restrict__ coarse,
                                const float* __restrict__ pts,
                                float* __restrict__ pB) {
    __shared__ float scx[1024], scy[1024], scz[1024];
    __shared__ float red[4];
    int b = blockIdx.x, ch = blockIdx.y, tid = threadIdx.x;
    const float* cb = coarse + (size_t)b * 3072;
    for (int i = tid; i < 1024; i += 256) {
        scx[i] = cb[i * 3]; scy[i] = cb[i * 3 + 1]; scz[i] = cb[i * 3 + 2];
    }
    __syncthreads();
    int p = ch * 64 + (tid >> 2);
    int quad = tid & 3;
    const float* pp = pts + (size_t)b * 6144 + p * 3;
    float px = pp[0], py = pp[1], pz = pp[2];
    float mn0 = FLT_MAX, mn1 = FLT_MAX, mn2 = FLT_MAX, mn3 = FLT_MAX;
    int m0 = quad * 256;
    for (int m = m0; m < m0 + 256; m += 4) {
        float dx, dy, dz;
        dx = px - scx[m];     dy = py - scy[m];     dz = pz - scz[m];
        mn0 = fminf(mn0, fmaf(dx, dx, fmaf(dy, dy, dz * dz)));
        dx = px - scx[m + 1]; dy = py - scy[m + 1]; dz = pz - scz[m + 1];
        mn1 = fminf(mn1, fmaf(dx, dx, fmaf(dy, dy, dz * dz)));
        dx = px - scx[m + 2]; dy = py - scy[m + 2]; dz = pz - scz[m + 2];
        mn2 = fminf(mn2, fmaf(dx, dx, fmaf(dy, dy, dz * dz)));
        dx = px - scx[m + 3]; dy = py - scy[m + 3]; dz = pz - scz[m + 3];
        mn3 = fminf(mn3, fmaf(dx, dx, fmaf(dy, dy, dz * dz)));
    }
    float mn = fminf(fminf(mn0, mn1), fminf(mn2, mn3));
    mn = fminf(mn, __shfl_xor(mn, 1));
    mn = fminf(mn, __shfl_xor(mn, 2));
    float s = (quad == 0) ? mn : 0.f;
#pragma unroll
    for (int off = 32; off > 0; off >>= 1) s += __shfl_down(s, off);
    int w = tid >> 6, lane = tid & 63;
    if (lane == 0) red[w] = s;
    __syncthreads();
    if (tid == 0) pB[b * 32 + ch] = red[0] + red[1] + red[2] + red[3];
}

__global__ void loss_kernel(const float* __restrict__ pA, const float* __restrict__ pB,
                            float* __restrict__ out) {
    __shared__ float rA[4], rB[4];
    int tid = threadIdx.x;
    float a = pA[tid] + pA[tid + 256];
    float b = pB[tid] + pB[tid + 256];
#pragma unroll
    for (int off = 32; off > 0; off >>= 1) {
        a += __shfl_down(a, off);
        b += __shfl_down(b, off);
    }
    int w = tid >> 6, lane = tid & 63;
    if (lane == 0) { rA[w] = a; rB[w] = b; }
    __syncthreads();
    if (tid == 0)
        out[0] = (rA[0] + rA[1] + rA[2] + rA[3]) / (16.f * 1024.f)
               + (rB[0] + rB[1] + rB[2] + rB[3]) / (16.f * 2048.f);
}

extern "C" void kernel_launch(void* const* d_in, const int* in_sizes, int n_in,
                              void* d_out, int out_size, void* d_ws, size_t ws_size,
                              hipStream_t stream) {
    const float* corrupted = (const float*)d_in[0];
    const float* pts = (const float*)d_in[1];
    const float* w1 = (const float*)d_in[2];   const float* b1 = (const float*)d_in[3];
    const float* w2 = (const float*)d_in[4];   const float* b2 = (const float*)d_in[5];
    const float* w3 = (const float*)d_in[6];   const float* b3 = (const float*)d_in[7];
    const float* w4 = (const float*)d_in[8];   const float* b4 = (const float*)d_in[9];
    const float* w5 = (const float*)d_in[10];  const float* b5 = (const float*)d_in[11];
    const float* fw1 = (const float*)d_in[12]; const float* fb1 = (const float*)d_in[13];
    const float* fw2 = (const float*)d_in[14]; const float* fb2 = (const float*)d_in[15];
    const float* fw3 = (const float*)d_in[16]; const float* fb3 = (const float*)d_in[17];
    float* out = (float*)d_out;

    char* ws = (char*)d_ws;
    u16*   cathi  = (u16*)(ws);                   // [32768][512] bf16 hi   32 MB
    u16*   catlo  = (u16*)(ws + 33554432);        // [32768][512] bf16 lo   32 MB
    float* ut     = (float*)(ws + 67108864);      // 64 MB (aliased dist/fcpart)
    u16*   dist   = (u16*)ut;                     // [8][2048][2048] u16 keys
    float* fcpart = ut;
    int*   idx    = (int*)  (ws + 134217728);     // [32768][20]
    float* sqn    = (float*)(ws + 136839168);     // [32768]
    u16*   Bw5h   = (u16*)(ws + 136970240);       // 1 MB
    u16*   Bw5l   = (u16*)(ws + 138018816);       // 1 MB
    float* bt34   = (float*)(ws + 139067392);
    float* bt2    = bt34;
    float* bt3    = bt34 + 128;
    float* bt4    = bt34 + 384;
    char*  G      = ws + 139071488;               // gpart region (1 MB), dual-use
    u16*   Be2h   = (u16*)(G);
    u16*   Be2l   = (u16*)(G + 16384);
    u16*   Be3h   = (u16*)(G + 32768);
    u16*   Be3l   = (u16*)(G + 65536);
    u16*   Be4h   = (u16*)(G + 98304);
    u16*   Be4l   = (u16*)(G + 229376);
    float* wtf    = (float*)(G + 360448);
    float* bt1    = (float*)(G + 362496);
    float* gpart  = (float*)G;
    float* feat   = (float*)(ws + 140120064);
    float* h1     = (float*)(ws + 140185600);
    float* h2     = (float*)(ws + 140251136);
    float* coarse = (float*)(ws + 140316672);
    float* pA     = (float*)(ws + 140513280);
    float* pB     = (float*)(ws + 140515328);

    // ---- one batched prep for all weights ----
    prep_all_kernel<<<2406, 256, 0, stream>>>(w1, b1, w2, b2, w3, b3, w4, b4, w5,
                                              Bw5h, Bw5l, Be2h, Be2l, Be3h, Be3l,
                                              Be4h, Be4l, bt2, bt3, bt4, wtf, bt1);

    // ---- conv1 ----
    select3_kernel<<<2048, 256, 0, stream>>>(corrupted, idx);
    conv1_kernel<<<16384, 256, 0, stream>>>(corrupted, wtf, bt1, ut);
    gather_max_kernel<64><<<8192, 256, 0, stream>>>(ut, idx, cathi, catlo, 0, sqn);

    // ---- convs 2-4: symmetric hi-only MFMA gram (u16 keys, 2 groups of z=8) ----
    auto conv = [&](int coloff, int C, int Cout, const u16* Beh, const u16* Bel,
                    const float* btp, int colout, bool needNextSqn) {
        int N2 = 2 * Cout;
        for (int g = 0; g < 2; ++g) {
            size_t off = ((size_t)g * 8 * N_) * 512 + coloff;
            mfma_gemm<3><<<dim3(136, 1, 8), 256, 0, stream>>>(
                cathi + off, (long long)N_ * 512, 512,
                cathi + off, catlo + off, (long long)N_ * 512, 512,
                sqn + (size_t)g * 8 * N_, N_,
                (float*)dist, (long long)(N_ * N_ / 2), N_, C);
            select_kernel<<<4096, 256, 0, stream>>>(dist, idx + (size_t)g * 8 * N_ * KNN);
        }
        mfma_gemm<0><<<dim3(256, N2 / 128, 1), 256, 0, stream>>>(
            cathi + coloff, 0, 512,
            Beh, Bel, 0, C,
            btp, 0,
            ut, 0, N2, C);
        float* sq = needNextSqn ? sqn : nullptr;
        if (Cout == 64)       gather_max_kernel<64><<<8192, 256, 0, stream>>>(ut, idx, cathi, catlo, colout, sq);
        else if (Cout == 128) gather_max_kernel<128><<<16384, 256, 0, stream>>>(ut, idx, cathi, catlo, colout, sq);
        else                  gather_max_kernel<256><<<32768, 256, 0, stream>>>(ut, idx, cathi, catlo, colout, sq);
    };
    conv(0, 64, 64, Be2h, Be2l, bt2, 64, true);
    conv(64, 64, 128, Be3h, Be3l, bt3, 128, true);
    conv(128, 128, 256, Be4h, Be4l, bt4, 256, false);

    // ---- w5 + leaky + max over N (fused epilogue, split-2) ----
    mfma_gemm<1><<<dim3(256, 8, 1), 256, 0, stream>>>(
        cathi, 0, 512,
        Bw5h, Bw5l, 0, 512,
        b5, 0,
        gpart, 0, 1024, 512);
    featmax_kernel<<<64, 256, 0, stream>>>(gpart, feat);

    // ---- FCs: k-split partials + reduce (deterministic) ----
    fc_part_kernel<<<dim3(16, 16), 256, 0, stream>>>(feat, fw1, fcpart, 1024);
    fc_reduce_kernel<<<64, 256, 0, stream>>>(fcpart, fb1, h1, 1024, 1);
    fc_part_kernel<<<dim3(16, 16), 256, 0, stream>>>(h1, fw2, fcpart, 1024);
    fc_reduce_kernel<<<64, 256, 0, stream>>>(fcpart, fb2, h2, 1024, 1);
    fc_part_kernel<<<dim3(48, 16), 256, 0, stream>>>(h2, fw3, fcpart, 3072);
    fc_reduce_kernel<<<192, 256, 0, stream>>>(fcpart, fb3, coarse, 3072, 0);

    chamferA_kernel<<<dim3(16, 32), 256, 0, stream>>>(coarse, pts, pA);
    chamferB_kernel<<<dim3(16, 32), 256, 0, stream>>>(coarse, pts, pB);
    loss_kernel<<<1, 256, 0, stream>>>(pA, pB, out);
}

// Round 19
// 561.880 us; speedup vs baseline: 1.1532x; 1.0178x over previous
//
#include <hip/hip_runtime.h>
#include <float.h>

#define B_ 16
#define N_ 2048
#define KNN 20

typedef unsigned short u16;
typedef __attribute__((ext_vector_type(8))) short bf16x8;
typedef __attribute__((ext_vector_type(4))) float f32x4;

typedef const __attribute__((address_space(1))) unsigned gas_t;
typedef __attribute__((address_space(3))) unsigned las_t;

__device__ inline u16 bfhi(float v) {
    union { float f; unsigned u; } x; x.f = v;
    unsigned r = x.u + 0x7FFFu + ((x.u >> 16) & 1u);
    return (u16)(r >> 16);
}
__device__ inline u16 bflo(float v, u16 h) {
    union { unsigned u; float f; } y; y.u = ((unsigned)h) << 16;
    return bfhi(v - y.f);
}
__device__ inline unsigned fkey(float v) {
    union { float f; unsigned u; } x;
    x.f = fmaxf(v, 0.f);
    return x.u & 0x7FFFFFFFu;
}
__device__ inline u16 fkey16(float v) { return (u16)(fkey(v) >> 15); }
__device__ inline unsigned umin_(unsigned a, unsigned b) { return a < b ? a : b; }

// payload (element index) encoding per keys-per-lane layout
template <int MODE>
__device__ inline unsigned payof(int i, int lane) {
    if (MODE == 0) return ((unsigned)(i >> 2) << 8) + (unsigned)lane * 4u + (unsigned)(i & 3);
    else           return ((unsigned)(i >> 3) << 9) + (unsigned)lane * 8u + (unsigned)(i & 7);
}

// ---------------- bitonic sort across 64 lanes (ascending by key) ----------------
template <bool P>
__device__ inline void bitonic64(unsigned& key, unsigned& pay, int lane) {
#pragma unroll
    for (int k = 2; k <= 64; k <<= 1) {
#pragma unroll
        for (int j = k >> 1; j > 0; j >>= 1) {
            unsigned ok = __shfl_xor(key, j);
            unsigned op = P ? __shfl_xor(pay, j) : 0u;
            bool up = ((lane & k) == 0);
            bool lower = ((lane & j) == 0);
            bool takeOther = (up == lower) ? (ok < key) : (ok > key);
            if (takeOther) { key = ok; if (P) pay = op; }
        }
    }
}

// ---------------- top-20-smallest via threshold filter (round-15 form) ----------------
template <int MODE>
__device__ inline void select20(const unsigned* kr, int lane,
                                unsigned* klist, unsigned* ilist,
                                int* __restrict__ outIdx) {
    unsigned lm = kr[0];
#pragma unroll
    for (int i = 1; i < 32; ++i) lm = umin_(lm, kr[i]);
    unsigned dummy = 0, sk = lm;
    bitonic64<false>(sk, dummy, lane);
    unsigned S = __shfl(sk, 19);
    unsigned c = 0;
#pragma unroll
    for (int i = 0; i < 32; ++i) c += (kr[i] <= S) ? 1u : 0u;
    unsigned incl = c;
#pragma unroll
    for (int d = 1; d < 64; d <<= 1) {
        unsigned t = __shfl_up(incl, d);
        if (lane >= d) incl += t;
    }
    unsigned stot = __shfl(incl, 63);
    unsigned pos = incl - c;
    klist[lane] = 0xFFFFFFFFu;
    __syncthreads();
#pragma unroll
    for (int i = 0; i < 32; ++i) {
        if (kr[i] <= S) {
            if (pos < 64u) {
                klist[pos] = kr[i];
                ilist[pos] = payof<MODE>(i, lane);
            }
            ++pos;
        }
    }
    __syncthreads();
    if (stot <= 64u) {
        unsigned key = klist[lane], pay = ilist[lane];
        bitonic64<true>(key, pay, lane);
        if (lane < KNN) outIdx[lane] = (int)pay;
    } else {
        unsigned taken = 0;
        for (int it = 0; it < KNN; ++it) {
            unsigned bk = 0xFFFFFFFFu; int bi = 0;
#pragma unroll
            for (int i = 0; i < 32; ++i) {
                bool better = (((taken >> i) & 1u) == 0u) && (kr[i] < bk);
                if (better) { bk = kr[i]; bi = i; }
            }
            unsigned bl = (unsigned)lane;
#pragma unroll
            for (int off = 32; off > 0; off >>= 1) {
                unsigned ok = __shfl_down(bk, off);
                unsigned ol = __shfl_down(bl, off);
                int oi = __shfl_down(bi, off);
                if (ok < bk) { bk = ok; bl = ol; bi = oi; }
            }
            bl = __shfl(bl, 0); bi = __shfl(bi, 0);
            if (lane == (int)bl) taken |= (1u << bi);
            if (lane == 0) outIdx[it] = (int)payof<MODE>(bi, (int)bl);
        }
    }
}

// select for convs 2-4: reads precomputed u16 keys (8 keys/lane/chunk)
__launch_bounds__(256)
__global__ void select_kernel(const u16* __restrict__ dist, int* __restrict__ idx_out) {
    __shared__ unsigned kl[4][64], il[4][64];
    int tid = threadIdx.x, w = tid >> 6, lane = tid & 63;
    size_t q = (size_t)blockIdx.x * 4 + w;
    const u16* src = dist + q * N_;
    unsigned kr[32];
#pragma unroll
    for (int j = 0; j < 4; ++j) {
        uint4 v = *(const uint4*)&src[j * 512 + lane * 8];
        const unsigned* pw = (const unsigned*)&v;
#pragma unroll
        for (int e = 0; e < 4; ++e) {
            kr[j * 8 + 2 * e]     = pw[e] & 0xFFFFu;
            kr[j * 8 + 2 * e + 1] = pw[e] >> 16;
        }
    }
    select20<1>(kr, lane, kl[w], il[w], idx_out + q * KNN);
}

// select for conv1: distances straight from 3-D coords; 16 queries per block
__launch_bounds__(256)
__global__ void select3_kernel(const float* __restrict__ x, int* __restrict__ idx_out) {
    __shared__ __align__(16) float cx[N_], cy[N_], cz[N_];
    __shared__ unsigned kl[4][64], il[4][64];
    int tid = threadIdx.x, blk = blockIdx.x;
    int b = blk >> 7, n0 = (blk & 127) * 16;
    for (int i = tid; i < N_; i += 256) {
        const float* p = x + (size_t)(b * N_ + i) * 3;
        cx[i] = p[0]; cy[i] = p[1]; cz[i] = p[2];
    }
    __syncthreads();
    int w = tid >> 6, lane = tid & 63;
    for (int r = 0; r < 4; ++r) {
        int q = n0 + r * 4 + w;
        float qx = cx[q], qy = cy[q], qz = cz[q];
        unsigned kr[32];
#pragma unroll
        for (int j = 0; j < 8; ++j) {
            float4 vx = *(const float4*)&cx[j * 256 + lane * 4];
            float4 vy = *(const float4*)&cy[j * 256 + lane * 4];
            float4 vz = *(const float4*)&cz[j * 256 + lane * 4];
            float dx, dy, dz;
            dx = qx - vx.x; dy = qy - vy.x; dz = qz - vz.x;
            kr[j * 4 + 0] = fkey(fmaf(dx, dx, fmaf(dy, dy, dz * dz)));
            dx = qx - vx.y; dy = qy - vy.y; dz = qz - vz.y;
            kr[j * 4 + 1] = fkey(fmaf(dx, dx, fmaf(dy, dy, dz * dz)));
            dx = qx - vx.z; dy = qy - vy.z; dz = qz - vz.z;
            kr[j * 4 + 2] = fkey(fmaf(dx, dx, fmaf(dy, dy, dz * dz)));
            dx = qx - vx.w; dy = qy - vy.w; dz = qz - vz.w;
            kr[j * 4 + 3] = fkey(fmaf(dx, dx, fmaf(dy, dy, dz * dz)));
        }
        select20<0>(kr, lane, kl[w], il[w], idx_out + ((size_t)(b * N_ + q)) * KNN);
    }
}

// ---------------- batched weight prep: w5 + 3 edge-Bs + conv1 wt + biases ----------------
__global__ void prep_all_kernel(const float* __restrict__ w1, const float* __restrict__ b1,
                                const float* __restrict__ w2, const float* __restrict__ b2,
                                const float* __restrict__ w3, const float* __restrict__ b3,
                                const float* __restrict__ w4, const float* __restrict__ b4,
                                const float* __restrict__ w5,
                                u16* __restrict__ Bw5h, u16* __restrict__ Bw5l,
                                u16* __restrict__ Be2h, u16* __restrict__ Be2l,
                                u16* __restrict__ Be3h, u16* __restrict__ Be3l,
                                u16* __restrict__ Be4h, u16* __restrict__ Be4l,
                                float* __restrict__ bt2, float* __restrict__ bt3,
                                float* __restrict__ bt4,
                                float* __restrict__ wtf, float* __restrict__ bt1) {
    int t = blockIdx.x * 256 + threadIdx.x;
    if (t < 524288) {
        int n = t / 512, k = t % 512;
        float v = w5[(size_t)k * 1024 + n];
        u16 h = bfhi(v);
        Bw5h[t] = h; Bw5l[t] = bflo(v, h);
    } else if (t < 532480) {
        int e = t - 524288;
        int d = e / 64, c = e % 64;
        float v = (d < 64) ? w2[c * 64 + d] : (w2[(64 + c) * 64 + (d - 64)] - w2[c * 64 + (d - 64)]);
        u16 h = bfhi(v);
        Be2h[e] = h; Be2l[e] = bflo(v, h);
    } else if (t < 548864) {
        int e = t - 532480;
        int d = e / 64, c = e % 64;
        float v = (d < 128) ? w3[c * 128 + d] : (w3[(64 + c) * 128 + (d - 128)] - w3[c * 128 + (d - 128)]);
        u16 h = bfhi(v);
        Be3h[e] = h; Be3l[e] = bflo(v, h);
    } else if (t < 614400) {
        int e = t - 548864;
        int d = e / 128, c = e % 128;
        float v = (d < 256) ? w4[c * 256 + d] : (w4[(128 + c) * 256 + (d - 256)] - w4[c * 256 + (d - 256)]);
        u16 h = bfhi(v);
        Be4h[e] = h; Be4l[e] = bflo(v, h);
    } else if (t < 614528) {
        int e = t - 614400;
        bt2[e] = (e < 64) ? 0.f : b2[e - 64];
    } else if (t < 614784) {
        int e = t - 614528;
        bt3[e] = (e < 128) ? 0.f : b3[e - 128];
    } else if (t < 615296) {
        int e = t - 614784;
        bt4[e] = (e < 256) ? 0.f : b4[e - 256];
    } else if (t < 615680) {
        int e = t - 615296;
        int c = e / 128, d = e % 128;
        float v = (d < 64) ? w1[c * 64 + d] : (w1[(3 + c) * 64 + (d - 64)] - w1[c * 64 + (d - 64)]);
        wtf[e] = v;
    } else if (t < 615808) {
        int e = t - 615680;
        bt1[e] = (e < 64) ? 0.f : b1[e - 64];
    }
}

// ---------------- bf16 MFMA GEMM, 128x128 tile, 4 waves (2x2) ----------------
// EPI 0/1: SPLIT-2 product (aH*bH + aH*bL), XCD-chunked mapping. LDS 48 KB -> 3 blocks/CU.
// EPI=3: u16 dist keys, HI-ONLY product, symmetric triangle grid. LDS 36 KB -> 4 blocks/CU.
template <int EPI>
__launch_bounds__(256, 2)
__global__ void mfma_gemm(const u16* __restrict__ Ah,
                          long long aZ, int lda,
                          const u16* __restrict__ Bh, const u16* __restrict__ Bl,
                          long long bZ, int ldb,
                          const float* __restrict__ ep, long long epZ,
                          float* __restrict__ out, long long outZ, int ldo,
                          int K) {
    __shared__ __align__(16) char smem[(EPI == 3) ? 36864 : 49152];
    u16* AsH = (u16*)(smem);
    u16* BsH = (u16*)(smem + 16384);
    u16* BsL = (u16*)(smem + 32768);   // only touched when EPI != 3
    u16 (*LTs)[136] = (u16(*)[136])(smem);   // alias, post-loop (EPI=3): 34816 B <= 36864
    __shared__ float red[2][128];
    int tid = threadIdx.x;
    int m0, n0, mt = 0;
    if (EPI == 3) {
        int t = blockIdx.x, rem = 16, bi = 0;
        while (t >= rem) { t -= rem; ++bi; --rem; }
        m0 = bi * 128; n0 = (bi + t) * 128;
    } else {
        int MT = gridDim.x, NT = gridDim.y;
        int f = blockIdx.x + blockIdx.y * MT;
        int xcd = f & 7, s = f >> 3;
        int sm = s / NT;
        int nt = s - sm * NT;
        mt = xcd * (MT >> 3) + sm;
        m0 = mt * 128; n0 = nt * 128;
    }
    int z = blockIdx.z;
    const u16* ah = Ah + (size_t)z * aZ;
    const u16* bh = Bh + (size_t)z * bZ;
    const u16* bl = Bl + (size_t)z * bZ;
    const float* epz = ep + (size_t)z * epZ;
    float* op = out + (size_t)z * outZ;

    int wid = tid >> 6, lane = tid & 63;
    int wm = wid >> 1, wn = wid & 1;
    int l15 = lane & 15, l4 = lane >> 4;
    int lrow8 = lane >> 3;
    int lg = lane & 7;

    f32x4 acc[4][4];
#pragma unroll
    for (int i = 0; i < 4; ++i)
#pragma unroll
        for (int j = 0; j < 4; ++j) acc[i][j] = (f32x4){0.f, 0.f, 0.f, 0.f};

    for (int k0 = 0; k0 < K; k0 += 64) {
        if (k0) __syncthreads();
#pragma unroll
        for (int ch = 0; ch < 4; ++ch) {
            int row = wid * 32 + ch * 8 + lrow8;
            int gsrc = lg ^ (row & 7);
            unsigned ldsoff = (unsigned)(wid * 32 + ch * 8) * 64;
            size_t ga = (size_t)(m0 + row) * lda + k0 + gsrc * 8;
            size_t gb = (size_t)(n0 + row) * ldb + k0 + gsrc * 8;
            __builtin_amdgcn_global_load_lds((gas_t*)(ah + ga), (las_t*)(AsH + ldsoff), 16, 0, 0);
            __builtin_amdgcn_global_load_lds((gas_t*)(bh + gb), (las_t*)(BsH + ldsoff), 16, 0, 0);
            if (EPI != 3)
                __builtin_amdgcn_global_load_lds((gas_t*)(bl + gb), (las_t*)(BsL + ldsoff), 16, 0, 0);
        }
        __syncthreads();
#pragma unroll
        for (int kk = 0; kk < 2; ++kk) {
            int ko_g = kk * 4 + l4;
            bf16x8 aH[4], bH[4], bL[4];
#pragma unroll
            for (int i = 0; i < 4; ++i) {
                int ra = wm * 64 + i * 16 + l15;
                int oa = ra * 64 + ((ko_g ^ (ra & 7)) << 3);
                aH[i] = *(const bf16x8*)&AsH[oa];
                int rb = wn * 64 + i * 16 + l15;
                int ob = rb * 64 + ((ko_g ^ (rb & 7)) << 3);
                bH[i] = *(const bf16x8*)&BsH[ob];
                if (EPI != 3) bL[i] = *(const bf16x8*)&BsL[ob];
            }
#pragma unroll
            for (int i = 0; i < 4; ++i)
#pragma unroll
                for (int j = 0; j < 4; ++j) {
                    acc[i][j] = __builtin_amdgcn_mfma_f32_16x16x32_bf16(aH[i], bH[j], acc[i][j], 0, 0, 0);
                    if (EPI != 3)
                        acc[i][j] = __builtin_amdgcn_mfma_f32_16x16x32_bf16(aH[i], bL[j], acc[i][j], 0, 0, 0);
                }
        }
    }

    if (EPI == 0) {
#pragma unroll
        for (int i = 0; i < 4; ++i)
#pragma unroll
            for (int r = 0; r < 4; ++r) {
                int grow = m0 + wm * 64 + i * 16 + l4 * 4 + r;
#pragma unroll
                for (int j = 0; j < 4; ++j) {
                    int col = n0 + wn * 64 + j * 16 + l15;
                    op[(size_t)grow * ldo + col] = acc[i][j][r] + epz[col];
                }
            }
    } else if (EPI == 1) {
        float pm[4];
#pragma unroll
        for (int j = 0; j < 4; ++j) {
            float v = -FLT_MAX;
#pragma unroll
            for (int i = 0; i < 4; ++i)
#pragma unroll
                for (int r = 0; r < 4; ++r) v = fmaxf(v, acc[i][j][r]);
            v = fmaxf(v, __shfl_xor(v, 16));
            v = fmaxf(v, __shfl_xor(v, 32));
            pm[j] = v;
        }
        if (l4 == 0) {
#pragma unroll
            for (int j = 0; j < 4; ++j) red[wm][wn * 64 + j * 16 + l15] = pm[j];
        }
        __syncthreads();
        if (tid < 128) {
            float v = fmaxf(red[0][tid], red[1][tid]) + epz[n0 + tid];
            v = (v > 0.f) ? v : 0.2f * v;
            op[(size_t)mt * ldo + n0 + tid] = v;
        }
    } else {
        u16* opu = (u16*)op;
#pragma unroll
        for (int i = 0; i < 4; ++i)
#pragma unroll
            for (int r = 0; r < 4; ++r) {
                int grow = m0 + wm * 64 + i * 16 + l4 * 4 + r;
                float sm = epz[grow];
#pragma unroll
                for (int j = 0; j < 4; ++j) {
                    int col = n0 + wn * 64 + j * 16 + l15;
                    opu[(size_t)grow * ldo + col] = fkey16(sm + epz[col] - 2.f * acc[i][j][r]);
                }
            }
        if (m0 != n0) {
            __syncthreads();
#pragma unroll
            for (int i = 0; i < 4; ++i)
#pragma unroll
                for (int j = 0; j < 4; ++j) {
                    int colL  = wn * 64 + j * 16 + l15;
                    int growL = wm * 64 + i * 16 + l4 * 4;
                    unsigned k0v = fkey16(epz[m0 + growL + 0] + epz[n0 + colL] - 2.f * acc[i][j][0]);
                    unsigned k1v = fkey16(epz[m0 + growL + 1] + epz[n0 + colL] - 2.f * acc[i][j][1]);
                    unsigned k2v = fkey16(epz[m0 + growL + 2] + epz[n0 + colL] - 2.f * acc[i][j][2]);
                    unsigned k3v = fkey16(epz[m0 + growL + 3] + epz[n0 + colL] - 2.f * acc[i][j][3]);
                    uint2 pk;
                    pk.x = k0v | (k1v << 16);
                    pk.y = k2v | (k3v << 16);
                    *(uint2*)&LTs[colL][growL] = pk;
                }
            __syncthreads();
            for (int rr0 = 0; rr0 < 128; rr0 += 8) {
                int rr = rr0 + (tid >> 5), cc = (tid & 31) * 4;
                uint2 v = *(const uint2*)&LTs[rr][cc];
                *(uint2*)&opu[(size_t)(n0 + rr) * ldo + m0 + cc] = v;
            }
        }
    }
}

// ---------------- conv1 direct GEMM (K=3) ----------------
__global__ void conv1_kernel(const float* __restrict__ x, const float* __restrict__ wt,
                             const float* __restrict__ bt, float* __restrict__ ut) {
    __shared__ float sw[3][128], sb[128];
    int tid = threadIdx.x;
    if (tid < 128) { sw[0][tid] = wt[tid]; sw[1][tid] = wt[128 + tid]; }
    else { int d = tid - 128; sw[2][d] = wt[256 + d]; sb[d] = bt[d]; }
    __syncthreads();
    int t = blockIdx.x * 256 + tid;
    int m = t >> 7, d = t & 127;
    const float* xm = x + (size_t)m * 3;
    float v = sb[d];
    v = fmaf(xm[0], sw[0][d], v);
    v = fmaf(xm[1], sw[1][d], v);
    v = fmaf(xm[2], sw[2][d], v);
    ut[(size_t)m * 128 + d] = v;
}

// ---------------- gather + leaky + max over k + fused next-conv sqnorm ----------------
template <int COUT>
__global__ void gather_max_kernel(const float* __restrict__ ut,
                                  const int* __restrict__ idx,
                                  u16* __restrict__ cathi, u16* __restrict__ catlo,
                                  int coloff, float* __restrict__ sqn_out) {
    const int P = 256 / COUT;
    int tid = threadIdx.x;
    int p = tid / COUT, d = tid % COUT;
    int nb = gridDim.x;
    int i = blockIdx.x;
    int half = (i >= (nb >> 1)) ? 1 : 0;
    int ii = i - half * (nb >> 1);
    int b = half * 8 + (ii & 7);
    int within = ii >> 3;
    int pt_base = b * 2048 + within * P;
    int pt = pt_base + p;
    int n = pt & 2047;
    __shared__ int sidx[P][KNN];
    __shared__ float wpart[4];
    for (int q = tid; q < P * KNN; q += 256) {
        int pp = q / KNN, kk = q % KNN;
        sidx[pp][kk] = idx[(size_t)(pt_base + pp) * KNN + kk];
    }
    __syncthreads();
    const int N2 = 2 * COUT;
    const float* utb = ut + (size_t)b * N_ * N2;
    float tval = utb[(size_t)n * N2 + COUT + d];
    float acc = -FLT_MAX;
#pragma unroll
    for (int k = 0; k < KNN; k++) {
        int j = __builtin_amdgcn_readfirstlane(sidx[p][k]);
        const float* rp = utb + (size_t)j * N2;
        float s = rp[d] + tval;
        s = (s > 0.f) ? s : 0.2f * s;
        acc = fmaxf(acc, s);
    }
    u16 h = bfhi(acc);
    u16 l = bflo(acc, h);
    cathi[(size_t)pt * 512 + coloff + d] = h;
    catlo[(size_t)pt * 512 + coloff + d] = l;
    if (sqn_out) {
        union { unsigned u; float f; } va, vb;
        va.u = ((unsigned)h) << 16; vb.u = ((unsigned)l) << 16;
        float v = va.f + vb.f;
        float sq = v * v;
#pragma unroll
        for (int off = 1; off < 64; off <<= 1) sq += __shfl_xor(sq, off);
        int wid = tid >> 6, lane = tid & 63;
        if (lane == 0) wpart[wid] = sq;
        __syncthreads();
        const int WPP = COUT / 64;
        if (tid < P) {
            float s2 = 0.f;
#pragma unroll
            for (int ww = 0; ww < WPP; ++ww) s2 += wpart[tid * WPP + ww];
            sqn_out[pt_base + tid] = s2;
        }
    }
}

// ---------------- feat = max over 16 row-blocks of gpart ----------------
__global__ void featmax_kernel(const float* __restrict__ gpart, float* __restrict__ feat) {
    int t = blockIdx.x * 256 + threadIdx.x;
    int b = t >> 10, d = t & 1023;
    float m = -FLT_MAX;
    for (int rb = 0; rb < 16; ++rb)
        m = fmaxf(m, gpart[(size_t)(b * 16 + rb) * 1024 + d]);
    feat[t] = m;
}

// ---------------- FC k-split: partials over 64-k chunks; W read exactly once ----------------
__global__ void fc_part_kernel(const float* __restrict__ in, const float* __restrict__ W,
                               float* __restrict__ part, int N) {
    __shared__ float sin_[16][64];
    __shared__ float red[3][16][64];
    int tid = threadIdx.x, lane = tid & 63, g = tid >> 6;
    int col = blockIdx.x * 64 + lane;
    int k0 = blockIdx.y * 64;
    for (int i = tid; i < 1024; i += 256)
        sin_[i >> 6][i & 63] = in[(i >> 6) * 1024 + k0 + (i & 63)];
    __syncthreads();
    float acc[16];
#pragma unroll
    for (int b = 0; b < 16; ++b) acc[b] = 0.f;
    int kk0 = g * 16;
#pragma unroll
    for (int k = kk0; k < kk0 + 16; ++k) {
        float wv = W[(size_t)(k0 + k) * N + col];
#pragma unroll
        for (int b = 0; b < 16; ++b) acc[b] = fmaf(sin_[b][k], wv, acc[b]);
    }
    if (g) {
#pragma unroll
        for (int b = 0; b < 16; ++b) red[g - 1][b][lane] = acc[b];
    }
    __syncthreads();
    if (g == 0) {
#pragma unroll
        for (int b = 0; b < 16; ++b) {
            float v = acc[b] + red[0][b][lane] + red[1][b][lane] + red[2][b][lane];
            part[((size_t)blockIdx.y * 16 + b) * N + col] = v;
        }
    }
}

__global__ void fc_reduce_kernel(const float* __restrict__ part, const float* __restrict__ bias,
                                 float* __restrict__ out, int N, int act) {
    int t = blockIdx.x * 256 + threadIdx.x;
    int b = t / N, col = t % N;
    float s = bias[col];
#pragma unroll
    for (int ks = 0; ks < 16; ++ks) s += part[((size_t)ks * 16 + b) * N + col];
    if (act) s = fmaxf(s, 0.f);
    out[(size_t)b * N + col] = s;
}

// ---------------- chamfer pass A ----------------
__launch_bounds__(256)
__global__ void chamferA_kernel(const float* __restrict__ coarse,
                                const float* __restrict__ pts,
                                float* __restrict__ pA) {
    __shared__ float spx[2048], spy[2048], spz[2048];
    __shared__ float red[4];
    int b = blockIdx.x, ch = blockIdx.y, tid = threadIdx.x;
    const float* pb = pts + (size_t)b * 6144;
    for (int i = tid; i < 2048; i += 256) {
        spx[i] = pb[i * 3]; spy[i] = pb[i * 3 + 1]; spz[i] = pb[i * 3 + 2];
    }
    __syncthreads();
    int q = ch * 32 + (tid >> 3);
    int oct = tid & 7;
    const float* cp = coarse + (size_t)b * 3072 + q * 3;
    float cx = cp[0], cy = cp[1], cz = cp[2];
    float mn0 = FLT_MAX, mn1 = FLT_MAX, mn2 = FLT_MAX, mn3 = FLT_MAX;
    int n0 = oct * 256;
    for (int n = n0; n < n0 + 256; n += 4) {
        float dx, dy, dz;
        dx = cx - spx[n];     dy = cy - spy[n];     dz = cz - spz[n];
        mn0 = fminf(mn0, fmaf(dx, dx, fmaf(dy, dy, dz * dz)));
        dx = cx - spx[n + 1]; dy = cy - spy[n + 1]; dz = cz - spz[n + 1];
        mn1 = fminf(mn1, fmaf(dx, dx, fmaf(dy, dy, dz * dz)));
        dx = cx - spx[n + 2]; dy = cy - spy[n + 2]; dz = cz - spz[n + 2];
        mn2 = fminf(mn2, fmaf(dx, dx, fmaf(dy, dy, dz * dz)));
        dx = cx - spx[n + 3]; dy = cy - spy[n + 3]; dz = cz - spz[n + 3];
        mn3 = fminf(mn3, fmaf(dx, dx, fmaf(dy, dy, dz * dz)));
    }
    float mn = fminf(fminf(mn0, mn1), fminf(mn2, mn3));
    mn = fminf(mn, __shfl_xor(mn, 1));
    mn = fminf(mn, __shfl_xor(mn, 2));
    mn = fminf(mn, __shfl_xor(mn, 4));
    float s = (oct == 0) ? mn : 0.f;
#pragma unroll
    for (int off = 32; off > 0; off >>= 1) s += __shfl_down(s, off);
    int w = tid >> 6, lane = tid & 63;
    if (lane == 0) red[w] = s;
    __syncthreads();
    if (tid == 0) pA[b * 32 + ch] = red[0] + red[1] + red[2] + red[3];
}

// ---------------- chamfer pass B ----------------
__launch_bounds__(256)
__global__ void chamferB_kernel(const float* __restrict__ coarse,
                                const float* __restrict__ pts,
                                float* __restrict__ pB) {
    __shared__ float scx[1024], scy[1024], scz[1024];
    __shared__ float red[4];
    int b = blockIdx.x, ch = blockIdx.y, tid = threadIdx.x;
    const float* cb = coarse + (size_t)b * 3072;
    for (int i = tid; i < 1024; i += 256) {
        scx[i] = cb[i * 3]; scy[i] = cb[i * 3 + 1]; scz[i] = cb[i * 3 + 2];
    }
    __syncthreads();
    int p = ch * 64 + (tid >> 2);
    int quad = tid & 3;
    const float* pp = pts + (size_t)b * 6144 + p * 3;
    float px = pp[0], py = pp[1], pz = pp[2];
    float mn0 = FLT_MAX, mn1 = FLT_MAX, mn2 = FLT_MAX, mn3 = FLT_MAX;
    int m0 = quad * 256;
    for (int m = m0; m < m0 + 256; m += 4) {
        float dx, dy, dz;
        dx = px - scx[m];     dy = py - scy[m];     dz = pz - scz[m];
        mn0 = fminf(mn0, fmaf(dx, dx, fmaf(dy, dy, dz * dz)));
        dx = px - scx[m + 1]; dy = py - scy[m + 1]; dz = pz - scz[m + 1];
        mn1 = fminf(mn1, fmaf(dx, dx, fmaf(dy, dy, dz * dz)));
        dx = px - scx[m + 2]; dy = py - scy[m + 2]; dz = pz - scz[m + 2];
        mn2 = fminf(mn2, fmaf(dx, dx, fmaf(dy, dy, dz * dz)));
        dx = px - scx[m + 3]; dy = py - scy[m + 3]; dz = pz - scz[m + 3];
        mn3 = fminf(mn3, fmaf(dx, dx, fmaf(dy, dy, dz * dz)));
    }
    float mn = fminf(fminf(mn0, mn1), fminf(mn2, mn3));
    mn = fminf(mn, __shfl_xor(mn, 1));
    mn = fminf(mn, __shfl_xor(mn, 2));
    float s = (quad == 0) ? mn : 0.f;
#pragma unroll
    for (int off = 32; off > 0; off >>= 1) s += __shfl_down(s, off);
    int w = tid >> 6, lane = tid & 63;
    if (lane == 0) red[w] = s;
    __syncthreads();
    if (tid == 0) pB[b * 32 + ch] = red[0] + red[1] + red[2] + red[3];
}

__global__ void loss_kernel(const float* __restrict__ pA, const float* __restrict__ pB,
                            float* __restrict__ out) {
    __shared__ float rA[4], rB[4];
    int tid = threadIdx.x;
    float a = pA[tid] + pA[tid + 256];
    float b = pB[tid] + pB[tid + 256];
#pragma unroll
    for (int off = 32; off > 0; off >>= 1) {
        a += __shfl_down(a, off);
        b += __shfl_down(b, off);
    }
    int w = tid >> 6, lane = tid & 63;
    if (lane == 0) { rA[w] = a; rB[w] = b; }
    __syncthreads();
    if (tid == 0)
        out[0] = (rA[0] + rA[1] + rA[2] + rA[3]) / (16.f * 1024.f)
               + (rB[0] + rB[1] + rB[2] + rB[3]) / (16.f * 2048.f);
}

extern "C" void kernel_launch(void* const* d_in, const int* in_sizes, int n_in,
                              void* d_out, int out_size, void* d_ws, size_t ws_size,
                              hipStream_t stream) {
    const float* corrupted = (const float*)d_in[0];
    const float* pts = (const float*)d_in[1];
    const float* w1 = (const float*)d_in[2];   const float* b1 = (const float*)d_in[3];
    const float* w2 = (const float*)d_in[4];   const float* b2 = (const float*)d_in[5];
    const float* w3 = (const float*)d_in[6];   const float* b3 = (const float*)d_in[7];
    const float* w4 = (const float*)d_in[8];   const float* b4 = (const float*)d_in[9];
    const float* w5 = (const float*)d_in[10];  const float* b5 = (const float*)d_in[11];
    const float* fw1 = (const float*)d_in[12]; const float* fb1 = (const float*)d_in[13];
    const float* fw2 = (const float*)d_in[14]; const float* fb2 = (const float*)d_in[15];
    const float* fw3 = (const float*)d_in[16]; const float* fb3 = (const float*)d_in[17];
    float* out = (float*)d_out;

    char* ws = (char*)d_ws;
    u16*   cathi  = (u16*)(ws);                   // [32768][512] bf16 hi   32 MB
    u16*   catlo  = (u16*)(ws + 33554432);        // [32768][512] bf16 lo   32 MB
    float* ut     = (float*)(ws + 67108864);      // 64 MB (aliased dist/fcpart)
    u16*   dist   = (u16*)ut;                     // [8][2048][2048] u16 keys
    float* fcpart = ut;
    int*   idx    = (int*)  (ws + 134217728);     // [32768][20]
    float* sqn    = (float*)(ws + 136839168);     // [32768]
    u16*   Bw5h   = (u16*)(ws + 136970240);       // 1 MB
    u16*   Bw5l   = (u16*)(ws + 138018816);       // 1 MB
    float* bt34   = (float*)(ws + 139067392);
    float* bt2    = bt34;
    float* bt3    = bt34 + 128;
    float* bt4    = bt34 + 384;
    char*  G      = ws + 139071488;               // gpart region (1 MB), dual-use
    u16*   Be2h   = (u16*)(G);
    u16*   Be2l   = (u16*)(G + 16384);
    u16*   Be3h   = (u16*)(G + 32768);
    u16*   Be3l   = (u16*)(G + 65536);
    u16*   Be4h   = (u16*)(G + 98304);
    u16*   Be4l   = (u16*)(G + 229376);
    float* wtf    = (float*)(G + 360448);
    float* bt1    = (float*)(G + 362496);
    float* gpart  = (float*)G;
    float* feat   = (float*)(ws + 140120064);
    float* h1     = (float*)(ws + 140185600);
    float* h2     = (float*)(ws + 140251136);
    float* coarse = (float*)(ws + 140316672);
    float* pA     = (float*)(ws + 140513280);
    float* pB     = (float*)(ws + 140515328);

    // ---- one batched prep for all weights ----
    prep_all_kernel<<<2406, 256, 0, stream>>>(w1, b1, w2, b2, w3, b3, w4, b4, w5,
                                              Bw5h, Bw5l, Be2h, Be2l, Be3h, Be3l,
                                              Be4h, Be4l, bt2, bt3, bt4, wtf, bt1);

    // ---- conv1 ----
    select3_kernel<<<2048, 256, 0, stream>>>(corrupted, idx);
    conv1_kernel<<<16384, 256, 0, stream>>>(corrupted, wtf, bt1, ut);
    gather_max_kernel<64><<<8192, 256, 0, stream>>>(ut, idx, cathi, catlo, 0, sqn);

    // ---- convs 2-4: symmetric hi-only MFMA gram (u16 keys, 2 groups of z=8) ----
    auto conv = [&](int coloff, int C, int Cout, const u16* Beh, const u16* Bel,
                    const float* btp, int colout, bool needNextSqn) {
        int N2 = 2 * Cout;
        for (int g = 0; g < 2; ++g) {
            size_t off = ((size_t)g * 8 * N_) * 512 + coloff;
            mfma_gemm<3><<<dim3(136, 1, 8), 256, 0, stream>>>(
                cathi + off, (long long)N_ * 512, 512,
                cathi + off, catlo + off, (long long)N_ * 512, 512,
                sqn + (size_t)g * 8 * N_, N_,
                (float*)dist, (long long)(N_ * N_ / 2), N_, C);
            select_kernel<<<4096, 256, 0, stream>>>(dist, idx + (size_t)g * 8 * N_ * KNN);
        }
        mfma_gemm<0><<<dim3(256, N2 / 128, 1), 256, 0, stream>>>(
            cathi + coloff, 0, 512,
            Beh, Bel, 0, C,
            btp, 0,
            ut, 0, N2, C);
        float* sq = needNextSqn ? sqn : nullptr;
        if (Cout == 64)       gather_max_kernel<64><<<8192, 256, 0, stream>>>(ut, idx, cathi, catlo, colout, sq);
        else if (Cout == 128) gather_max_kernel<128><<<16384, 256, 0, stream>>>(ut, idx, cathi, catlo, colout, sq);
        else                  gather_max_kernel<256><<<32768, 256, 0, stream>>>(ut, idx, cathi, catlo, colout, sq);
    };
    conv(0, 64, 64, Be2h, Be2l, bt2, 64, true);
    conv(64, 64, 128, Be3h, Be3l, bt3, 128, true);
    conv(128, 128, 256, Be4h, Be4l, bt4, 256, false);

    // ---- w5 + leaky + max over N (fused epilogue, split-2) ----
    mfma_gemm<1><<<dim3(256, 8, 1), 256, 0, stream>>>(
        cathi, 0, 512,
        Bw5h, Bw5l, 0, 512,
        b5, 0,
        gpart, 0, 1024, 512);
    featmax_kernel<<<64, 256, 0, stream>>>(gpart, feat);

    // ---- FCs: k-split partials + reduce (deterministic) ----
    fc_part_kernel<<<dim3(16, 16), 256, 0, stream>>>(feat, fw1, fcpart, 1024);
    fc_reduce_kernel<<<64, 256, 0, stream>>>(fcpart, fb1, h1, 1024, 1);
    fc_part_kernel<<<dim3(16, 16), 256, 0, stream>>>(h1, fw2, fcpart, 1024);
    fc_reduce_kernel<<<64, 256, 0, stream>>>(fcpart, fb2, h2, 1024, 1);
    fc_part_kernel<<<dim3(48, 16), 256, 0, stream>>>(h2, fw3, fcpart, 3072);
    fc_reduce_kernel<<<192, 256, 0, stream>>>(fcpart, fb3, coarse, 3072, 0);

    chamferA_kernel<<<dim3(16, 32), 256, 0, stream>>>(coarse, pts, pA);
    chamferB_kernel<<<dim3(16, 32), 256, 0, stream>>>(coarse, pts, pB);
    loss_kernel<<<1, 256, 0, stream>>>(pA, pB, out);
}